// Round 3
// baseline (441.404 us; speedup 1.0000x reference)
//
#include <hip/hip_runtime.h>
#include <math.h>

#define B_ 1024
#define I_ 256
#define N_ 1024
#define O_ 256
#define EPSV 1e-5f

// ---------------------------------------------------------------------------
// Pre-pass: row norms of x (per b) and column norms of G (per n), re & im.
// ---------------------------------------------------------------------------
__global__ __launch_bounds__(64) void pre_kernel(
    const float* __restrict__ x_re, const float* __restrict__ x_im,
    const float* __restrict__ G_re, const float* __restrict__ G_im,
    float* __restrict__ xsq_re, float* __restrict__ xsq_im,
    float* __restrict__ gsq_re, float* __restrict__ gsq_im)
{
    const int bid  = blockIdx.x;
    const int lane = threadIdx.x;
    if (bid < B_) {
        const float4* xr = (const float4*)(x_re + (size_t)bid * I_);
        const float4* xi = (const float4*)(x_im + (size_t)bid * I_);
        float4 a = xr[lane];
        float4 c = xi[lane];
        float sr = a.x*a.x + a.y*a.y + a.z*a.z + a.w*a.w;
        float si = c.x*c.x + c.y*c.y + c.z*c.z + c.w*c.w;
        #pragma unroll
        for (int off = 32; off > 0; off >>= 1) {
            sr += __shfl_down(sr, off);
            si += __shfl_down(si, off);
        }
        if (lane == 0) { xsq_re[bid] = sr; xsq_im[bid] = si; }
    } else {
        const int n = (bid - B_) * 64 + lane;
        float sr = 0.f, si = 0.f;
        for (int i = 0; i < I_; ++i) {
            float g = G_re[(size_t)i * N_ + n]; sr += g * g;
            float h = G_im[(size_t)i * N_ + n]; si += h * h;
        }
        gsq_re[n] = sr; gsq_im[n] = si;
    }
}

// ---------------------------------------------------------------------------
// Bias init (d_out is re-poisoned before every launch).
// ---------------------------------------------------------------------------
__global__ __launch_bounds__(256) void init_kernel(
    const float* __restrict__ b_re, const float* __restrict__ b_im,
    float* __restrict__ out)
{
    const int idx = blockIdx.x * 256 + threadIdx.x;
    const int q = idx & 127;
    const int o = q * 2;
    float4 v;
    v.x = b_re[o];     v.y = b_im[o];
    v.z = b_re[o + 1]; v.w = b_im[o + 1];
    *((float4*)out + idx) = v;
}

// ---------------------------------------------------------------------------
// phi GEMM: C = X @ G (re & im), epilogue phi = exp(-(xsq-2C+gsq)/max(s,eps))
// Tile 64x64, K-tile 32, 256 threads, 4x4 micro (2 B LDS / FMA).
// LDS double-buffered (70 KB) + register prefetch: ONE barrier per K-tile.
// Grid 16x16 = 256 blocks (grid-capped at 1 block/CU).
// ---------------------------------------------------------------------------
__global__ __launch_bounds__(256, 1) void phi_kernel(
    const float* __restrict__ Xr, const float* __restrict__ Xi,
    const float* __restrict__ Gr, const float* __restrict__ Gi,
    const float* __restrict__ xsq_re, const float* __restrict__ xsq_im,
    const float* __restrict__ gsq_re, const float* __restrict__ gsq_im,
    const float* __restrict__ s_re, const float* __restrict__ s_im,
    float* __restrict__ Pr, float* __restrict__ Pi)
{
    __shared__ float Ar[2][32][68], Ai[2][32][68];   // A^T: [k][m]
    __shared__ float Br[2][32][68], Bi[2][32][68];   // B:   [k][n]
    const int tid = threadIdx.x;
    const int tx = tid & 15, ty = tid >> 4;
    const int m0 = blockIdx.y * 64, n0 = blockIdx.x * 64;
    const int lm = tid >> 2, lq = tid & 3;    // A loader: row lm(0..63), k-quad lq
    const int lk = tid >> 4, ls = tid & 15;   // B loader: k-row lk(0..15), seg ls

    float cr[4][4] = {}, ci[4][4] = {};
    float4 ar0, ar1, ai0, ai1, br0, br1, bi0, bi1;

    const float* Arow = Xr + (size_t)(m0 + lm) * I_ + lq * 4;
    const float* Airow = Xi + (size_t)(m0 + lm) * I_ + lq * 4;
    const float* Brow = Gr + (size_t)lk * N_ + n0 + ls * 4;
    const float* Birow = Gi + (size_t)lk * N_ + n0 + ls * 4;

#define PHI_LOAD(k0)                                                     \
    ar0 = *(const float4*)(Arow + (k0));                                 \
    ar1 = *(const float4*)(Arow + (k0) + 16);                            \
    ai0 = *(const float4*)(Airow + (k0));                                \
    ai1 = *(const float4*)(Airow + (k0) + 16);                           \
    br0 = *(const float4*)(Brow + (size_t)(k0) * N_);                    \
    br1 = *(const float4*)(Brow + (size_t)((k0) + 16) * N_);             \
    bi0 = *(const float4*)(Birow + (size_t)(k0) * N_);                   \
    bi1 = *(const float4*)(Birow + (size_t)((k0) + 16) * N_);

#define PHI_STORE(buf)                                                   \
    {                                                                    \
        const int k = lq * 4;                                            \
        Ar[buf][k+0][lm] = ar0.x; Ar[buf][k+1][lm] = ar0.y;              \
        Ar[buf][k+2][lm] = ar0.z; Ar[buf][k+3][lm] = ar0.w;              \
        Ar[buf][k+16][lm] = ar1.x; Ar[buf][k+17][lm] = ar1.y;            \
        Ar[buf][k+18][lm] = ar1.z; Ar[buf][k+19][lm] = ar1.w;            \
        Ai[buf][k+0][lm] = ai0.x; Ai[buf][k+1][lm] = ai0.y;              \
        Ai[buf][k+2][lm] = ai0.z; Ai[buf][k+3][lm] = ai0.w;              \
        Ai[buf][k+16][lm] = ai1.x; Ai[buf][k+17][lm] = ai1.y;            \
        Ai[buf][k+18][lm] = ai1.z; Ai[buf][k+19][lm] = ai1.w;            \
        *(float4*)&Br[buf][lk][ls*4]      = br0;                         \
        *(float4*)&Br[buf][lk + 16][ls*4] = br1;                         \
        *(float4*)&Bi[buf][lk][ls*4]      = bi0;                         \
        *(float4*)&Bi[buf][lk + 16][ls*4] = bi1;                         \
    }

    PHI_LOAD(0);
    PHI_STORE(0);
    __syncthreads();

    const int NKT = I_ / 32;   // 8
    for (int kt = 0; kt < NKT; ++kt) {
        const int buf = kt & 1;
        if (kt + 1 < NKT) { PHI_LOAD((kt + 1) * 32); }
        #pragma unroll
        for (int kk = 0; kk < 32; ++kk) {
            float4 a_r = *(const float4*)&Ar[buf][kk][ty*4];
            float4 a_i = *(const float4*)&Ai[buf][kk][ty*4];
            float4 b_r = *(const float4*)&Br[buf][kk][tx*4];
            float4 b_i = *(const float4*)&Bi[buf][kk][tx*4];
            float arr[4] = {a_r.x, a_r.y, a_r.z, a_r.w};
            float aii[4] = {a_i.x, a_i.y, a_i.z, a_i.w};
            float brr[4] = {b_r.x, b_r.y, b_r.z, b_r.w};
            float bii[4] = {b_i.x, b_i.y, b_i.z, b_i.w};
            #pragma unroll
            for (int i = 0; i < 4; ++i)
                #pragma unroll
                for (int j = 0; j < 4; ++j) {
                    cr[i][j] = fmaf(arr[i], brr[j], cr[i][j]);
                    ci[i][j] = fmaf(aii[i], bii[j], ci[i][j]);
                }
        }
        if (kt + 1 < NKT) {
            PHI_STORE(buf ^ 1);
            __syncthreads();
        }
    }

    #pragma unroll
    for (int i = 0; i < 4; ++i) {
        const int m = m0 + ty * 4 + i;
        const float xr  = xsq_re[m];
        const float xi2 = xsq_im[m];
        float4 pr4, pi4;
        float* prp = &pr4.x;
        float* pip = &pi4.x;
        #pragma unroll
        for (int j = 0; j < 4; ++j) {
            const int n = n0 + tx * 4 + j;
            const float vr = xr  - 2.f * cr[i][j] + gsq_re[n];
            const float vi = xi2 - 2.f * ci[i][j] + gsq_im[n];
            prp[j] = __expf(-vr / fmaxf(s_re[n], EPSV));
            pip[j] = __expf(-vi / fmaxf(s_im[n], EPSV));
        }
        *(float4*)(Pr + (size_t)m * N_ + n0 + tx * 4) = pr4;
        *(float4*)(Pi + (size_t)m * N_ + n0 + tx * 4) = pi4;
    }
#undef PHI_LOAD
#undef PHI_STORE
}

// ---------------------------------------------------------------------------
// Complex GEMM, split-K=8: y += (Pr + iPi) @ (Wr + iWi), atomically onto
// bias-initialized out. Tile 64x64, K-chunk 128 (4 K-tiles of 32),
// 256 threads, 4x4 complex micro (1 B LDS / FMA). LDS dbuf + reg prefetch.
// Grid 4 x 16 x 8 = 512 blocks -> 2 blocks/CU, 8 waves/CU.
// ---------------------------------------------------------------------------
__global__ __launch_bounds__(256, 2) void y_kernel(
    const float* __restrict__ Pr, const float* __restrict__ Pi,
    const float* __restrict__ Wr, const float* __restrict__ Wi,
    float* __restrict__ out)
{
    __shared__ float Apr[2][32][68], Api[2][32][68];  // P^T: [k][m]
    __shared__ float Bwr[2][32][68], Bwi[2][32][68];  // W:   [k][n]
    const int tid = threadIdx.x;
    const int tx = tid & 15, ty = tid >> 4;
    const int m0 = blockIdx.y * 64, n0 = blockIdx.x * 64;
    const int kbase = blockIdx.z * 128;
    const int lm = tid >> 2, lq = tid & 3;
    const int lk = tid >> 4, ls = tid & 15;

    float yr[4][4] = {}, yi[4][4] = {};
    float4 pr0, pr1, pi0, pi1, wr0, wr1, wi0, wi1;

    const float* Prow = Pr + (size_t)(m0 + lm) * N_ + kbase + lq * 4;
    const float* Pirow = Pi + (size_t)(m0 + lm) * N_ + kbase + lq * 4;
    const float* Wrow = Wr + (size_t)(kbase + lk) * O_ + n0 + ls * 4;
    const float* Wirow = Wi + (size_t)(kbase + lk) * O_ + n0 + ls * 4;

#define Y_LOAD(k0)                                                       \
    pr0 = *(const float4*)(Prow + (k0));                                 \
    pr1 = *(const float4*)(Prow + (k0) + 16);                            \
    pi0 = *(const float4*)(Pirow + (k0));                                \
    pi1 = *(const float4*)(Pirow + (k0) + 16);                           \
    wr0 = *(const float4*)(Wrow + (size_t)(k0) * O_);                    \
    wr1 = *(const float4*)(Wrow + (size_t)((k0) + 16) * O_);             \
    wi0 = *(const float4*)(Wirow + (size_t)(k0) * O_);                   \
    wi1 = *(const float4*)(Wirow + (size_t)((k0) + 16) * O_);

#define Y_STORE(buf)                                                     \
    {                                                                    \
        const int k = lq * 4;                                            \
        Apr[buf][k+0][lm] = pr0.x; Apr[buf][k+1][lm] = pr0.y;            \
        Apr[buf][k+2][lm] = pr0.z; Apr[buf][k+3][lm] = pr0.w;            \
        Apr[buf][k+16][lm] = pr1.x; Apr[buf][k+17][lm] = pr1.y;          \
        Apr[buf][k+18][lm] = pr1.z; Apr[buf][k+19][lm] = pr1.w;          \
        Api[buf][k+0][lm] = pi0.x; Api[buf][k+1][lm] = pi0.y;            \
        Api[buf][k+2][lm] = pi0.z; Api[buf][k+3][lm] = pi0.w;            \
        Api[buf][k+16][lm] = pi1.x; Api[buf][k+17][lm] = pi1.y;          \
        Api[buf][k+18][lm] = pi1.z; Api[buf][k+19][lm] = pi1.w;          \
        *(float4*)&Bwr[buf][lk][ls*4]      = wr0;                        \
        *(float4*)&Bwr[buf][lk + 16][ls*4] = wr1;                        \
        *(float4*)&Bwi[buf][lk][ls*4]      = wi0;                        \
        *(float4*)&Bwi[buf][lk + 16][ls*4] = wi1;                        \
    }

    Y_LOAD(0);
    Y_STORE(0);
    __syncthreads();

    const int NKT = 4;   // 128 / 32
    for (int kt = 0; kt < NKT; ++kt) {
        const int buf = kt & 1;
        if (kt + 1 < NKT) { Y_LOAD((kt + 1) * 32); }
        #pragma unroll
        for (int kk = 0; kk < 32; ++kk) {
            float4 a_r = *(const float4*)&Apr[buf][kk][ty*4];
            float4 a_i = *(const float4*)&Api[buf][kk][ty*4];
            float4 b_r = *(const float4*)&Bwr[buf][kk][tx*4];
            float4 b_i = *(const float4*)&Bwi[buf][kk][tx*4];
            float arr[4] = {a_r.x, a_r.y, a_r.z, a_r.w};
            float aii[4] = {a_i.x, a_i.y, a_i.z, a_i.w};
            float brr[4] = {b_r.x, b_r.y, b_r.z, b_r.w};
            float bii[4] = {b_i.x, b_i.y, b_i.z, b_i.w};
            #pragma unroll
            for (int i = 0; i < 4; ++i)
                #pragma unroll
                for (int j = 0; j < 4; ++j) {
                    yr[i][j] = fmaf(arr[i],  brr[j], yr[i][j]);
                    yr[i][j] = fmaf(-aii[i], bii[j], yr[i][j]);
                    yi[i][j] = fmaf(arr[i],  bii[j], yi[i][j]);
                    yi[i][j] = fmaf(aii[i],  brr[j], yi[i][j]);
                }
        }
        if (kt + 1 < NKT) {
            Y_STORE(buf ^ 1);
            __syncthreads();
        }
    }

    #pragma unroll
    for (int i = 0; i < 4; ++i) {
        const int m = m0 + ty * 4 + i;
        #pragma unroll
        for (int j = 0; j < 4; ++j) {
            const int n = n0 + tx * 4 + j;
            atomicAdd(out + ((size_t)m * O_ + n) * 2,     yr[i][j]);
            atomicAdd(out + ((size_t)m * O_ + n) * 2 + 1, yi[i][j]);
        }
    }
#undef Y_LOAD
#undef Y_STORE
}

extern "C" void kernel_launch(void* const* d_in, const int* in_sizes, int n_in,
                              void* d_out, int out_size, void* d_ws, size_t ws_size,
                              hipStream_t stream) {
    const float* x_re = (const float*)d_in[0];
    const float* x_im = (const float*)d_in[1];
    const float* G_re = (const float*)d_in[2];
    const float* G_im = (const float*)d_in[3];
    const float* s_re = (const float*)d_in[4];
    const float* s_im = (const float*)d_in[5];
    const float* W_re = (const float*)d_in[6];
    const float* W_im = (const float*)d_in[7];
    const float* b_re = (const float*)d_in[8];
    const float* b_im = (const float*)d_in[9];
    float* out = (float*)d_out;

    float* ws = (float*)d_ws;
    float* Pr     = ws;
    float* Pi     = Pr + (size_t)B_ * N_;
    float* xsq_re = Pi + (size_t)B_ * N_;
    float* xsq_im = xsq_re + B_;
    float* gsq_re = xsq_im + B_;
    float* gsq_im = gsq_re + N_;

    pre_kernel<<<B_ + N_ / 64, 64, 0, stream>>>(
        x_re, x_im, G_re, G_im, xsq_re, xsq_im, gsq_re, gsq_im);

    init_kernel<<<(B_ * O_ * 2 / 4) / 256, 256, 0, stream>>>(b_re, b_im, out);

    phi_kernel<<<dim3(N_ / 64, B_ / 64), 256, 0, stream>>>(
        x_re, x_im, G_re, G_im, xsq_re, xsq_im, gsq_re, gsq_im,
        s_re, s_im, Pr, Pi);

    y_kernel<<<dim3(O_ / 64, B_ / 64, 8), 256, 0, stream>>>(
        Pr, Pi, W_re, W_im, out);
}

// Round 4
// 133.939 us; speedup vs baseline: 3.2956x; 3.2956x over previous
//
#include <hip/hip_runtime.h>
#include <math.h>

#define B_ 1024
#define I_ 256
#define N_ 1024
#define O_ 256
#define EPSV 1e-5f

typedef unsigned short u16;
typedef short bf16x8 __attribute__((ext_vector_type(8)));   // 8 bf16 = 4 VGPRs
typedef float f32x4 __attribute__((ext_vector_type(4)));
typedef int i32x4 __attribute__((ext_vector_type(4)));

__device__ inline u16 f2bf(float f) {
    union { float f; unsigned int u; } v; v.f = f;
    unsigned int r = v.u + 0x7FFFu + ((v.u >> 16) & 1u);   // round-to-nearest-even
    return (u16)(r >> 16);
}

// ---------------------------------------------------------------------------
// Pre-pass: xsq row norms + X fp32->bf16 convert (blocks 0..B_-1),
//           gsq column norms of G (blocks B_..B_+15).
// ---------------------------------------------------------------------------
__global__ __launch_bounds__(64) void pre_kernel(
    const float* __restrict__ x_re, const float* __restrict__ x_im,
    const float* __restrict__ G_re, const float* __restrict__ G_im,
    u16* __restrict__ Xr, u16* __restrict__ Xi,
    float* __restrict__ xsq_re, float* __restrict__ xsq_im,
    float* __restrict__ gsq_re, float* __restrict__ gsq_im)
{
    const int bid = blockIdx.x, lane = threadIdx.x;
    if (bid < B_) {
        float4 a = *((const float4*)(x_re + (size_t)bid * I_) + lane);
        float4 c = *((const float4*)(x_im + (size_t)bid * I_) + lane);
        ushort4 ab, cb;
        ab.x = f2bf(a.x); ab.y = f2bf(a.y); ab.z = f2bf(a.z); ab.w = f2bf(a.w);
        cb.x = f2bf(c.x); cb.y = f2bf(c.y); cb.z = f2bf(c.z); cb.w = f2bf(c.w);
        *(ushort4*)(Xr + (size_t)bid * I_ + lane * 4) = ab;
        *(ushort4*)(Xi + (size_t)bid * I_ + lane * 4) = cb;
        float sr = a.x*a.x + a.y*a.y + a.z*a.z + a.w*a.w;
        float si = c.x*c.x + c.y*c.y + c.z*c.z + c.w*c.w;
        #pragma unroll
        for (int off = 32; off > 0; off >>= 1) {
            sr += __shfl_down(sr, off);
            si += __shfl_down(si, off);
        }
        if (lane == 0) { xsq_re[bid] = sr; xsq_im[bid] = si; }
    } else {
        const int n = (bid - B_) * 64 + lane;
        float sr = 0.f, si = 0.f;
        for (int i = 0; i < I_; ++i) {
            float g = G_re[(size_t)i * N_ + n]; sr += g * g;
            float h = G_im[(size_t)i * N_ + n]; si += h * h;
        }
        gsq_re[n] = sr; gsq_im[n] = si;
    }
}

// ---------------------------------------------------------------------------
// Transpose + fp32->bf16 convert: in fp32 [R][C] -> out bf16 [C][R].
// blockIdx.z selects (in0,out0) vs (in1,out1). 64x64 tiles, 256 threads.
// ---------------------------------------------------------------------------
__global__ __launch_bounds__(256) void transconv_kernel(
    const float* __restrict__ in0, const float* __restrict__ in1,
    u16* __restrict__ out0, u16* __restrict__ out1, int R, int C)
{
    __shared__ float tile[64][68];   // 68: 16B-aligned rows, non-pow2 bank stride
    const float* in = blockIdx.z ? in1 : in0;
    u16* out = blockIdx.z ? out1 : out0;
    const int r0 = blockIdx.y * 64, c0 = blockIdx.x * 64;
    const int t = threadIdx.x;
    const int lr = t >> 2, lq = t & 3;
    #pragma unroll
    for (int j = 0; j < 4; ++j) {
        float4 v = *(const float4*)(in + (size_t)(r0 + lr) * C + c0 + lq * 16 + j * 4);
        *(float4*)&tile[lr][lq * 16 + j * 4] = v;
    }
    __syncthreads();
    const int oc = t >> 2, oq = t & 3;
    __align__(16) u16 tmp[16];
    #pragma unroll
    for (int e = 0; e < 16; ++e)
        tmp[e] = f2bf(tile[oq * 16 + e][oc]);
    u16* dst = out + (size_t)(c0 + oc) * R + r0 + oq * 16;
    *(int4*)dst = *(const int4*)tmp;
    *((int4*)dst + 1) = *((const int4*)tmp + 1);
}

// ---------------------------------------------------------------------------
// Bias init (d_out is re-poisoned before every launch).
// ---------------------------------------------------------------------------
__global__ __launch_bounds__(256) void init_kernel(
    const float* __restrict__ b_re, const float* __restrict__ b_im,
    float* __restrict__ out)
{
    const int idx = blockIdx.x * 256 + threadIdx.x;
    const int q = idx & 127;
    const int o = q * 2;
    float4 v;
    v.x = b_re[o];     v.y = b_im[o];
    v.z = b_re[o + 1]; v.w = b_im[o + 1];
    *((float4*)out + idx) = v;
}

// ---------------------------------------------------------------------------
// phi GEMM via MFMA (one component per blockIdx.z):
//   C = X @ G  (K = I_ = 256), epilogue phi = exp(-(xsq - 2C + gsq)/max(s,eps))
// Tile 64x64, 4 waves in 2x2, each wave 32x32 = 2x2 fragments of 16x16x32.
// LDS: A[m][k] (k-contig), B^T[n][k] (k-contig) per verified fragment layouts.
// Grid (16, 16, 2) = 512 blocks.
// ---------------------------------------------------------------------------
__global__ __launch_bounds__(256) void phi_mfma(
    const u16* __restrict__ Xr, const u16* __restrict__ Xi,
    const u16* __restrict__ GTr, const u16* __restrict__ GTi,
    const float* __restrict__ xsq_re, const float* __restrict__ xsq_im,
    const float* __restrict__ gsq_re, const float* __restrict__ gsq_im,
    const float* __restrict__ s_re, const float* __restrict__ s_im,
    u16* __restrict__ Pr, u16* __restrict__ Pi)
{
    __shared__ u16 As[64][40];   // [m][k], row stride 40 u16 = 80 B
    __shared__ u16 Bs[64][40];   // [n][k]
    const int z = blockIdx.z;
    const u16* X  = z ? Xi : Xr;
    const u16* GT = z ? GTi : GTr;
    const float* xsq = z ? xsq_im : xsq_re;
    const float* gsq = z ? gsq_im : gsq_re;
    const float* s   = z ? s_im : s_re;
    u16* P = z ? Pi : Pr;

    const int t = threadIdx.x;
    const int m0 = blockIdx.y * 64, n0 = blockIdx.x * 64;
    const int w = t >> 6, l = t & 63;
    const int quad = l >> 4, l16 = l & 15;
    const int mw = (w >> 1) * 32, nw = (w & 1) * 32;
    const int lr = t >> 2, lseg = t & 3;   // staging: row lr(0..63), 16B seg

    f32x4 acc[2][2] = {};

    for (int kt = 0; kt < I_ / 32; ++kt) {
        const int k0 = kt * 32;
        float4 av = *(const float4*)(X  + (size_t)(m0 + lr) * I_ + k0 + lseg * 8);
        float4 bv = *(const float4*)(GT + (size_t)(n0 + lr) * I_ + k0 + lseg * 8);
        __syncthreads();
        *(float4*)&As[lr][lseg * 8] = av;
        *(float4*)&Bs[lr][lseg * 8] = bv;
        __syncthreads();
        bf16x8 af[2], bfr[2];
        af[0]  = *(const bf16x8*)&As[mw + l16][quad * 8];
        af[1]  = *(const bf16x8*)&As[mw + 16 + l16][quad * 8];
        bfr[0] = *(const bf16x8*)&Bs[nw + l16][quad * 8];
        bfr[1] = *(const bf16x8*)&Bs[nw + 16 + l16][quad * 8];
        #pragma unroll
        for (int mt = 0; mt < 2; ++mt)
            #pragma unroll
            for (int nt = 0; nt < 2; ++nt)
                acc[mt][nt] = __builtin_amdgcn_mfma_f32_16x16x32_bf16(
                    af[mt], bfr[nt], acc[mt][nt], 0, 0, 0);
    }

    // Epilogue. C/D layout: col = lane&15, row = quad*4 + reg.
    #pragma unroll
    for (int mt = 0; mt < 2; ++mt)
        #pragma unroll
        for (int nt = 0; nt < 2; ++nt) {
            const int col = n0 + nw + nt * 16 + l16;
            const float gq = gsq[col];
            const float inv_s = 1.0f / fmaxf(s[col], EPSV);
            #pragma unroll
            for (int r = 0; r < 4; ++r) {
                const int row = m0 + mw + mt * 16 + quad * 4 + r;
                const float v = xsq[row] - 2.0f * acc[mt][nt][r] + gq;
                P[(size_t)row * N_ + col] = f2bf(__expf(-v * inv_s));
            }
        }
}

// ---------------------------------------------------------------------------
// Complex GEMM via MFMA, split-K=8:
//   re += Pr@Wr - Pi@Wi ; im += Pr@Wi + Pi@Wr   (K = N_ = 1024)
// -Pi obtained by XORing bf16 sign bits (no extra accumulators).
// Tile 64x64, 4 waves 2x2, K-chunk 128. Grid (4, 16, 8) = 512 blocks.
// Partials atomicAdd onto bias-initialized out.
// ---------------------------------------------------------------------------
__global__ __launch_bounds__(256) void y_mfma(
    const u16* __restrict__ Pr, const u16* __restrict__ Pi,
    const u16* __restrict__ WTr, const u16* __restrict__ WTi,
    float* __restrict__ out)
{
    __shared__ u16 Ps[2][64][40];   // [comp][m][k]
    __shared__ u16 Ws[2][64][40];   // [comp][n][k]
    const int t = threadIdx.x;
    const int m0 = blockIdx.y * 64, n0 = blockIdx.x * 64, kb = blockIdx.z * 128;
    const int w = t >> 6, l = t & 63;
    const int quad = l >> 4, l16 = l & 15;
    const int mw = (w >> 1) * 32, nw = (w & 1) * 32;
    const int sc = t >> 7, sr = (t >> 1) & 63, sh = t & 1;  // staging split
    const u16* Pc = sc ? Pi : Pr;
    const u16* Wc = sc ? WTi : WTr;

    f32x4 accRe[2][2] = {}, accIm[2][2] = {};

    for (int kt = 0; kt < 4; ++kt) {
        const int k0 = kb + kt * 32;
        float4 pv0 = *(const float4*)(Pc + (size_t)(m0 + sr) * N_ + k0 + sh * 16);
        float4 pv1 = *(const float4*)(Pc + (size_t)(m0 + sr) * N_ + k0 + sh * 16 + 8);
        float4 wv0 = *(const float4*)(Wc + (size_t)(n0 + sr) * N_ + k0 + sh * 16);
        float4 wv1 = *(const float4*)(Wc + (size_t)(n0 + sr) * N_ + k0 + sh * 16 + 8);
        __syncthreads();
        *(float4*)&Ps[sc][sr][sh * 16]     = pv0;
        *(float4*)&Ps[sc][sr][sh * 16 + 8] = pv1;
        *(float4*)&Ws[sc][sr][sh * 16]     = wv0;
        *(float4*)&Ws[sc][sr][sh * 16 + 8] = wv1;
        __syncthreads();

        bf16x8 ar[2], ai[2], an[2], br[2], bi[2];
        #pragma unroll
        for (int mt = 0; mt < 2; ++mt) {
            ar[mt] = *(const bf16x8*)&Ps[0][mw + mt * 16 + l16][quad * 8];
            ai[mt] = *(const bf16x8*)&Ps[1][mw + mt * 16 + l16][quad * 8];
            i32x4 tv = (*(const i32x4*)&ai[mt]) ^ 0x80008000;   // negate bf16 pairs
            an[mt] = *(const bf16x8*)&tv;
        }
        #pragma unroll
        for (int nt = 0; nt < 2; ++nt) {
            br[nt] = *(const bf16x8*)&Ws[0][nw + nt * 16 + l16][quad * 8];
            bi[nt] = *(const bf16x8*)&Ws[1][nw + nt * 16 + l16][quad * 8];
        }
        #pragma unroll
        for (int mt = 0; mt < 2; ++mt)
            #pragma unroll
            for (int nt = 0; nt < 2; ++nt) {
                accRe[mt][nt] = __builtin_amdgcn_mfma_f32_16x16x32_bf16(
                    ar[mt], br[nt], accRe[mt][nt], 0, 0, 0);
                accRe[mt][nt] = __builtin_amdgcn_mfma_f32_16x16x32_bf16(
                    an[mt], bi[nt], accRe[mt][nt], 0, 0, 0);
                accIm[mt][nt] = __builtin_amdgcn_mfma_f32_16x16x32_bf16(
                    ar[mt], bi[nt], accIm[mt][nt], 0, 0, 0);
                accIm[mt][nt] = __builtin_amdgcn_mfma_f32_16x16x32_bf16(
                    ai[mt], br[nt], accIm[mt][nt], 0, 0, 0);
            }
    }

    #pragma unroll
    for (int mt = 0; mt < 2; ++mt)
        #pragma unroll
        for (int nt = 0; nt < 2; ++nt) {
            const int col = n0 + nw + nt * 16 + l16;
            #pragma unroll
            for (int r = 0; r < 4; ++r) {
                const int row = m0 + mw + mt * 16 + quad * 4 + r;
                atomicAdd(out + ((size_t)row * O_ + col) * 2,     accRe[mt][nt][r]);
                atomicAdd(out + ((size_t)row * O_ + col) * 2 + 1, accIm[mt][nt][r]);
            }
        }
}

extern "C" void kernel_launch(void* const* d_in, const int* in_sizes, int n_in,
                              void* d_out, int out_size, void* d_ws, size_t ws_size,
                              hipStream_t stream) {
    const float* x_re = (const float*)d_in[0];
    const float* x_im = (const float*)d_in[1];
    const float* G_re = (const float*)d_in[2];
    const float* G_im = (const float*)d_in[3];
    const float* s_re = (const float*)d_in[4];
    const float* s_im = (const float*)d_in[5];
    const float* W_re = (const float*)d_in[6];
    const float* W_im = (const float*)d_in[7];
    const float* b_re = (const float*)d_in[8];
    const float* b_im = (const float*)d_in[9];
    float* out = (float*)d_out;

    u16* Xr_bf = (u16*)d_ws;                  // [B][I]
    u16* Xi_bf = Xr_bf + (size_t)B_ * I_;
    u16* GT_r  = Xi_bf + (size_t)B_ * I_;     // [N][I]
    u16* GT_i  = GT_r + (size_t)N_ * I_;
    u16* WT_r  = GT_i + (size_t)N_ * I_;      // [O][N]
    u16* WT_i  = WT_r + (size_t)O_ * N_;
    u16* Pr    = WT_i + (size_t)O_ * N_;      // [B][N]
    u16* Pi    = Pr + (size_t)B_ * N_;
    float* xsq_re = (float*)(Pi + (size_t)B_ * N_);
    float* xsq_im = xsq_re + B_;
    float* gsq_re = xsq_im + B_;
    float* gsq_im = gsq_re + N_;

    pre_kernel<<<B_ + N_ / 64, 64, 0, stream>>>(
        x_re, x_im, G_re, G_im, Xr_bf, Xi_bf,
        xsq_re, xsq_im, gsq_re, gsq_im);

    // G [I][N] -> GT [N][I]
    transconv_kernel<<<dim3(N_ / 64, I_ / 64, 2), 256, 0, stream>>>(
        G_re, G_im, GT_r, GT_i, I_, N_);

    // W [N][O] -> WT [O][N]
    transconv_kernel<<<dim3(O_ / 64, N_ / 64, 2), 256, 0, stream>>>(
        W_re, W_im, WT_r, WT_i, N_, O_);

    init_kernel<<<(B_ * O_ * 2 / 4) / 256, 256, 0, stream>>>(b_re, b_im, out);

    phi_mfma<<<dim3(N_ / 64, B_ / 64, 2), 256, 0, stream>>>(
        Xr_bf, Xi_bf, GT_r, GT_i, xsq_re, xsq_im, gsq_re, gsq_im,
        s_re, s_im, Pr, Pi);

    y_mfma<<<dim3(O_ / 64, B_ / 64, 8), 256, 0, stream>>>(
        Pr, Pi, WT_r, WT_i, out);
}

// Round 5
// 117.222 us; speedup vs baseline: 3.7655x; 1.1426x over previous
//
#include <hip/hip_runtime.h>
#include <math.h>

#define B_ 1024
#define I_ 256
#define N_ 1024
#define O_ 256
#define EPSV 1e-5f

typedef unsigned short u16;
typedef short bf16x8 __attribute__((ext_vector_type(8)));   // 8 bf16 = 4 VGPRs
typedef float f32x4 __attribute__((ext_vector_type(4)));
typedef int i32x4 __attribute__((ext_vector_type(4)));

__device__ inline u16 f2bf(float f) {
    union { float f; unsigned int u; } v; v.f = f;
    unsigned int r = v.u + 0x7FFFu + ((v.u >> 16) & 1u);   // round-to-nearest-even
    return (u16)(r >> 16);
}

// 64x64 transpose + fp32->bf16: in [R][C] fp32 -> out [C][R] bf16.
__device__ inline void transconv64(const float* __restrict__ in,
                                   u16* __restrict__ out, int R, int C,
                                   int r0, int c0, int t, float (*tile)[68]) {
    const int lr = t >> 2, lq = t & 3;
    #pragma unroll
    for (int j = 0; j < 4; ++j) {
        float4 v = *(const float4*)(in + (size_t)(r0 + lr) * C + c0 + lq * 16 + j * 4);
        *(float4*)&tile[lr][lq * 16 + j * 4] = v;
    }
    __syncthreads();
    const int oc = t >> 2, oq = t & 3;
    __align__(16) u16 tmp[16];
    #pragma unroll
    for (int e = 0; e < 16; ++e) tmp[e] = f2bf(tile[oq * 16 + e][oc]);
    u16* dst = out + (size_t)(c0 + oc) * R + r0 + oq * 16;
    *(int4*)dst = *(const int4*)tmp;
    *((int4*)dst + 1) = *((const int4*)tmp + 1);
}

// ---------------------------------------------------------------------------
// Fused prep: one launch does
//   blk [0,256):    X fp32->bf16 + xsq row norms (4 rows/block, 1 wave/row)
//   blk [256,272):  gsq column norms of G (64 cols/block, LDS reduce)
//   blk [272,400):  G [I][N] -> GT [N][I] bf16 (2 comps x 4 x 16 tiles)
//   blk [400,528):  W [N][O] -> WT [O][N] bf16 (2 comps x 16 x 4 tiles)
//   blk [528,1040): bias init of out (d_out is re-poisoned every launch)
// ---------------------------------------------------------------------------
__global__ __launch_bounds__(256) void prep_kernel(
    const float* __restrict__ x_re, const float* __restrict__ x_im,
    const float* __restrict__ G_re, const float* __restrict__ G_im,
    const float* __restrict__ W_re, const float* __restrict__ W_im,
    const float* __restrict__ b_re, const float* __restrict__ b_im,
    u16* __restrict__ Xr, u16* __restrict__ Xi,
    u16* __restrict__ GTr, u16* __restrict__ GTi,
    u16* __restrict__ WTr, u16* __restrict__ WTi,
    float* __restrict__ xsq_re, float* __restrict__ xsq_im,
    float* __restrict__ gsq_re, float* __restrict__ gsq_im,
    float* __restrict__ out)
{
    __shared__ float smem[64][68];   // transpose tile / gsq reduce scratch
    const int blk = blockIdx.x, t = threadIdx.x;

    if (blk < 256) {
        const int w = t >> 6, l = t & 63;
        const int row = blk * 4 + w;
        float4 a = *((const float4*)(x_re + (size_t)row * I_) + l);
        float4 c = *((const float4*)(x_im + (size_t)row * I_) + l);
        ushort4 ab, cb;
        ab.x = f2bf(a.x); ab.y = f2bf(a.y); ab.z = f2bf(a.z); ab.w = f2bf(a.w);
        cb.x = f2bf(c.x); cb.y = f2bf(c.y); cb.z = f2bf(c.z); cb.w = f2bf(c.w);
        *(ushort4*)(Xr + (size_t)row * I_ + l * 4) = ab;
        *(ushort4*)(Xi + (size_t)row * I_ + l * 4) = cb;
        float sr = a.x*a.x + a.y*a.y + a.z*a.z + a.w*a.w;
        float si = c.x*c.x + c.y*c.y + c.z*c.z + c.w*c.w;
        #pragma unroll
        for (int off = 32; off > 0; off >>= 1) {
            sr += __shfl_down(sr, off);
            si += __shfl_down(si, off);
        }
        if (l == 0) { xsq_re[row] = sr; xsq_im[row] = si; }
    } else if (blk < 272) {
        const int l = t & 63, w = t >> 6;
        const int n = (blk - 256) * 64 + l;
        float sr = 0.f, si = 0.f;
        for (int i = w * 64; i < w * 64 + 64; ++i) {
            float g = G_re[(size_t)i * N_ + n]; sr += g * g;
            float h = G_im[(size_t)i * N_ + n]; si += h * h;
        }
        float (*red)[64] = (float(*)[64])smem;
        red[w][l] = sr; red[4 + w][l] = si;
        __syncthreads();
        if (w == 0) {
            gsq_re[n] = red[0][l] + red[1][l] + red[2][l] + red[3][l];
            gsq_im[n] = red[4][l] + red[5][l] + red[6][l] + red[7][l];
        }
    } else if (blk < 400) {
        const int local = blk - 272;
        const int z = local >> 6, rem = local & 63;
        const int rt = rem >> 4, ct = rem & 15;   // 4 x 16 tiles
        transconv64(z ? G_im : G_re, z ? GTi : GTr, I_, N_,
                    rt * 64, ct * 64, t, smem);
    } else if (blk < 528) {
        const int local = blk - 400;
        const int z = local >> 6, rem = local & 63;
        const int rt = rem >> 2, ct = rem & 3;    // 16 x 4 tiles
        transconv64(z ? W_im : W_re, z ? WTi : WTr, N_, O_,
                    rt * 64, ct * 64, t, smem);
    } else {
        const int idx = (blk - 528) * 256 + t;    // 0..131071 float4s
        const int q = idx & 127;
        const int o = q * 2;
        float4 v;
        v.x = b_re[o];     v.y = b_im[o];
        v.z = b_re[o + 1]; v.w = b_im[o + 1];
        *((float4*)out + idx) = v;
    }
}

// ---------------------------------------------------------------------------
// phi GEMM via MFMA (component per blockIdx.z): C = X @ G^T (K = 256),
// epilogue phi = exp(-(xsq - 2C + gsq)/max(s,eps)), stored bf16.
// SINGLE-PHASE: full K in LDS (67.6 KB), one barrier, then 32 MFMAs/wave.
// Tile 64x64, 4 waves 2x2. Grid (16,16,2) = 512 -> 2 blocks/CU.
// LDS stride 264 u16 (rows +4 dwords mod 32): frag reads 2-way (free);
// staging chunks c = ls + 4j keep b128 writes <=2-way.
// ---------------------------------------------------------------------------
__global__ __launch_bounds__(256) void phi_mfma(
    const u16* __restrict__ Xr, const u16* __restrict__ Xi,
    const u16* __restrict__ GTr, const u16* __restrict__ GTi,
    const float* __restrict__ xsq_re, const float* __restrict__ xsq_im,
    const float* __restrict__ gsq_re, const float* __restrict__ gsq_im,
    const float* __restrict__ s_re, const float* __restrict__ s_im,
    u16* __restrict__ Pr, u16* __restrict__ Pi)
{
    __shared__ u16 As[64][264];   // [m][k 0..255]
    __shared__ u16 Bs[64][264];   // [n][k 0..255]
    const int z = blockIdx.z;
    const u16* X  = z ? Xi : Xr;
    const u16* GT = z ? GTi : GTr;
    const float* xsq = z ? xsq_im : xsq_re;
    const float* gsq = z ? gsq_im : gsq_re;
    const float* s   = z ? s_im : s_re;
    u16* P = z ? Pi : Pr;

    const int t = threadIdx.x;
    const int m0 = blockIdx.y * 64, n0 = blockIdx.x * 64;
    const int w = t >> 6, l = t & 63;
    const int quad = l >> 4, l16 = l & 15;
    const int mw = (w >> 1) * 32, nw = (w & 1) * 32;
    const int lr = t >> 2, ls = t & 3;

    const u16* Xrow = X  + (size_t)(m0 + lr) * I_;
    const u16* Grow = GT + (size_t)(n0 + lr) * I_;
    #pragma unroll
    for (int j = 0; j < 8; ++j) {
        const int c = (ls + 4 * j) * 8;       // chunk offset in u16
        *(float4*)&As[lr][c] = *(const float4*)(Xrow + c);
        *(float4*)&Bs[lr][c] = *(const float4*)(Grow + c);
    }
    __syncthreads();

    f32x4 acc[2][2] = {};
    #pragma unroll
    for (int ks = 0; ks < 8; ++ks) {
        const int k = ks * 32 + quad * 8;
        bf16x8 af[2], bf[2];
        af[0] = *(const bf16x8*)&As[mw + l16][k];
        af[1] = *(const bf16x8*)&As[mw + 16 + l16][k];
        bf[0] = *(const bf16x8*)&Bs[nw + l16][k];
        bf[1] = *(const bf16x8*)&Bs[nw + 16 + l16][k];
        #pragma unroll
        for (int mt = 0; mt < 2; ++mt)
            #pragma unroll
            for (int nt = 0; nt < 2; ++nt)
                acc[mt][nt] = __builtin_amdgcn_mfma_f32_16x16x32_bf16(
                    af[mt], bf[nt], acc[mt][nt], 0, 0, 0);
    }

    // C/D layout: col = lane&15, row = quad*4 + reg.
    #pragma unroll
    for (int mt = 0; mt < 2; ++mt)
        #pragma unroll
        for (int nt = 0; nt < 2; ++nt) {
            const int col = n0 + nw + nt * 16 + l16;
            const float gq = gsq[col];
            const float inv_s = 1.0f / fmaxf(s[col], EPSV);
            #pragma unroll
            for (int r = 0; r < 4; ++r) {
                const int row = m0 + mw + mt * 16 + quad * 4 + r;
                const float v = xsq[row] - 2.0f * acc[mt][nt][r] + gq;
                P[(size_t)row * N_ + col] = f2bf(__expf(-v * inv_s));
            }
        }
}

// ---------------------------------------------------------------------------
// Complex GEMM via MFMA, split-K=8 (chunks of 128):
//   re += Pr@Wr - Pi@Wi ; im += Pr@Wi + Pi@Wr   (K = N_ = 1024)
// SINGLE-PHASE: 4 matrices x 64x128 in LDS (69.6 KB), one barrier,
// 64 MFMAs/wave. Tile 64x64, 4 waves 2x2. Grid (4,16,8) = 512.
// Partials atomicAdd onto bias-initialized out.
// ---------------------------------------------------------------------------
__global__ __launch_bounds__(256) void y_mfma(
    const u16* __restrict__ Pr, const u16* __restrict__ Pi,
    const u16* __restrict__ WTr, const u16* __restrict__ WTi,
    float* __restrict__ out)
{
    __shared__ u16 Ps[2][64][136];   // [comp][m][k 0..127]
    __shared__ u16 Ws[2][64][136];   // [comp][n][k 0..127]
    const int t = threadIdx.x;
    const int m0 = blockIdx.y * 64, n0 = blockIdx.x * 64, kb = blockIdx.z * 128;
    const int w = t >> 6, l = t & 63;
    const int quad = l >> 4, l16 = l & 15;
    const int mw = (w >> 1) * 32, nw = (w & 1) * 32;
    const int lr = t >> 2, ls = t & 3;

    const u16* Pr_row = Pr  + (size_t)(m0 + lr) * N_ + kb;
    const u16* Pi_row = Pi  + (size_t)(m0 + lr) * N_ + kb;
    const u16* Wr_row = WTr + (size_t)(n0 + lr) * N_ + kb;
    const u16* Wi_row = WTi + (size_t)(n0 + lr) * N_ + kb;
    #pragma unroll
    for (int j = 0; j < 4; ++j) {
        const int c = (ls + 4 * j) * 8;       // chunk offset in u16
        *(float4*)&Ps[0][lr][c] = *(const float4*)(Pr_row + c);
        *(float4*)&Ps[1][lr][c] = *(const float4*)(Pi_row + c);
        *(float4*)&Ws[0][lr][c] = *(const float4*)(Wr_row + c);
        *(float4*)&Ws[1][lr][c] = *(const float4*)(Wi_row + c);
    }
    __syncthreads();

    f32x4 accRe[2][2] = {}, accIm[2][2] = {};
    #pragma unroll
    for (int ks = 0; ks < 4; ++ks) {
        const int k = ks * 32 + quad * 8;
        bf16x8 ar[2], ai[2], an[2], br[2], bi[2];
        #pragma unroll
        for (int mt = 0; mt < 2; ++mt) {
            ar[mt] = *(const bf16x8*)&Ps[0][mw + mt * 16 + l16][k];
            ai[mt] = *(const bf16x8*)&Ps[1][mw + mt * 16 + l16][k];
            i32x4 tv = (*(const i32x4*)&ai[mt]) ^ 0x80008000;   // negate pairs
            an[mt] = *(const bf16x8*)&tv;
        }
        #pragma unroll
        for (int nt = 0; nt < 2; ++nt) {
            br[nt] = *(const bf16x8*)&Ws[0][nw + nt * 16 + l16][k];
            bi[nt] = *(const bf16x8*)&Ws[1][nw + nt * 16 + l16][k];
        }
        #pragma unroll
        for (int mt = 0; mt < 2; ++mt)
            #pragma unroll
            for (int nt = 0; nt < 2; ++nt) {
                accRe[mt][nt] = __builtin_amdgcn_mfma_f32_16x16x32_bf16(
                    ar[mt], br[nt], accRe[mt][nt], 0, 0, 0);
                accRe[mt][nt] = __builtin_amdgcn_mfma_f32_16x16x32_bf16(
                    an[mt], bi[nt], accRe[mt][nt], 0, 0, 0);
                accIm[mt][nt] = __builtin_amdgcn_mfma_f32_16x16x32_bf16(
                    ar[mt], bi[nt], accIm[mt][nt], 0, 0, 0);
                accIm[mt][nt] = __builtin_amdgcn_mfma_f32_16x16x32_bf16(
                    ai[mt], br[nt], accIm[mt][nt], 0, 0, 0);
            }
    }

    #pragma unroll
    for (int mt = 0; mt < 2; ++mt)
        #pragma unroll
        for (int nt = 0; nt < 2; ++nt) {
            const int col = n0 + nw + nt * 16 + l16;
            #pragma unroll
            for (int r = 0; r < 4; ++r) {
                const int row = m0 + mw + mt * 16 + quad * 4 + r;
                atomicAdd(out + ((size_t)row * O_ + col) * 2,     accRe[mt][nt][r]);
                atomicAdd(out + ((size_t)row * O_ + col) * 2 + 1, accIm[mt][nt][r]);
            }
        }
}

extern "C" void kernel_launch(void* const* d_in, const int* in_sizes, int n_in,
                              void* d_out, int out_size, void* d_ws, size_t ws_size,
                              hipStream_t stream) {
    const float* x_re = (const float*)d_in[0];
    const float* x_im = (const float*)d_in[1];
    const float* G_re = (const float*)d_in[2];
    const float* G_im = (const float*)d_in[3];
    const float* s_re = (const float*)d_in[4];
    const float* s_im = (const float*)d_in[5];
    const float* W_re = (const float*)d_in[6];
    const float* W_im = (const float*)d_in[7];
    const float* b_re = (const float*)d_in[8];
    const float* b_im = (const float*)d_in[9];
    float* out = (float*)d_out;

    u16* Xr_bf = (u16*)d_ws;                  // [B][I]
    u16* Xi_bf = Xr_bf + (size_t)B_ * I_;
    u16* GT_r  = Xi_bf + (size_t)B_ * I_;     // [N][I]
    u16* GT_i  = GT_r + (size_t)N_ * I_;
    u16* WT_r  = GT_i + (size_t)N_ * I_;      // [O][N]
    u16* WT_i  = WT_r + (size_t)O_ * N_;
    u16* Pr    = WT_i + (size_t)O_ * N_;      // [B][N]
    u16* Pi    = Pr + (size_t)B_ * N_;
    float* xsq_re = (float*)(Pi + (size_t)B_ * N_);
    float* xsq_im = xsq_re + B_;
    float* gsq_re = xsq_im + B_;
    float* gsq_im = gsq_re + N_;

    prep_kernel<<<1040, 256, 0, stream>>>(
        x_re, x_im, G_re, G_im, W_re, W_im, b_re, b_im,
        Xr_bf, Xi_bf, GT_r, GT_i, WT_r, WT_i,
        xsq_re, xsq_im, gsq_re, gsq_im, out);

    phi_mfma<<<dim3(N_ / 64, B_ / 64, 2), 256, 0, stream>>>(
        Xr_bf, Xi_bf, GT_r, GT_i, xsq_re, xsq_im, gsq_re, gsq_im,
        s_re, s_im, Pr, Pi);

    y_mfma<<<dim3(O_ / 64, B_ / 64, 8), 256, 0, stream>>>(
        Pr, Pi, WT_r, WT_i, out);
}

// Round 6
// 100.179 us; speedup vs baseline: 4.4061x; 1.1701x over previous
//
#include <hip/hip_runtime.h>
#include <math.h>

#define B_ 1024
#define I_ 256
#define N_ 1024
#define O_ 256
#define EPSV 1e-5f

typedef unsigned short u16;
typedef short bf16x8 __attribute__((ext_vector_type(8)));   // 8 bf16 = 4 VGPRs
typedef float f32x4 __attribute__((ext_vector_type(4)));
typedef int i32x4 __attribute__((ext_vector_type(4)));

__device__ inline u16 f2bf(float f) {
    union { float f; unsigned int u; } v; v.f = f;
    unsigned int r = v.u + 0x7FFFu + ((v.u >> 16) & 1u);   // round-to-nearest-even
    return (u16)(r >> 16);
}

// Fragment-order storage: per (row16-tile, k32-tile) store 64 chunks of 8 bf16.
// chunk slot = quad*16 + (row&15), quad = (k>>3)&3; matches MFMA A/B layout
// (m|n = lane&15, k = (lane>>4)*8 + j) validated by R4/R5. Tile = 512 u16 = 1 KB.

// ---------------------------------------------------------------------------
// Generic transpose + convert into fragment order:
// in fp32 [R][C] -> out frag-order over rows=C (the 16-dim), k=R (ktiles=R/32).
// Handles one 64x64 tile at (r0, c0). tile LDS stride 69 (2-way banks only).
// ---------------------------------------------------------------------------
__device__ inline void transconv_frag(const float* __restrict__ in,
                                      u16* __restrict__ out, int R, int C,
                                      int r0, int c0, int t, float (*tile)[69]) {
    const int lr = t >> 2, lq = t & 3;
    #pragma unroll
    for (int j = 0; j < 4; ++j) {
        float4 v = *(const float4*)(in + (size_t)(r0 + lr) * C + c0 + lq * 16 + j * 4);
        *(float4*)&tile[lr][lq * 16 + j * 4] = v;
    }
    __syncthreads();
    const int oc = t >> 2, oq = t & 3;
    const int row = c0 + oc;
    const int ktiles = R >> 5;
    #pragma unroll
    for (int h = 0; h < 2; ++h) {
        const int k0 = r0 + oq * 16 + h * 8;
        const int kt = k0 >> 5, quad = (k0 >> 3) & 3;
        __align__(16) u16 tmp[8];
        #pragma unroll
        for (int e = 0; e < 8; ++e)
            tmp[e] = f2bf(tile[oq * 16 + h * 8 + e][oc]);
        const size_t off = ((size_t)((row >> 4) * ktiles + kt)) * 512
                         + (quad * 16 + (row & 15)) * 8;
        *(int4*)(out + off) = *(const int4*)tmp;
    }
}

// ---------------------------------------------------------------------------
// Fused prep (one dispatch, 784 blocks):
//   [0,256):   xsq row norms of x (4 rows/block, 1 wave/row)
//   [256,272): gsq column norms of G
//   [272,528): X fp32 -> frag-order bf16 (both comps; 4 tiles/block)
//   [528,656): G [I][N] -> GT frag-order (rows=n, k=i)
//   [656,784): W [N][O] -> WT frag-order (rows=o, k=n)
// ---------------------------------------------------------------------------
__global__ __launch_bounds__(256) void prep_kernel(
    const float* __restrict__ x_re, const float* __restrict__ x_im,
    const float* __restrict__ G_re, const float* __restrict__ G_im,
    const float* __restrict__ W_re, const float* __restrict__ W_im,
    u16* __restrict__ Xfr, u16* __restrict__ Xfi,
    u16* __restrict__ GTfr, u16* __restrict__ GTfi,
    u16* __restrict__ WTfr, u16* __restrict__ WTfi,
    float* __restrict__ xsq_re, float* __restrict__ xsq_im,
    float* __restrict__ gsq_re, float* __restrict__ gsq_im)
{
    __shared__ float smem[64][69];
    const int blk = blockIdx.x, t = threadIdx.x;

    if (blk < 256) {
        const int w = t >> 6, l = t & 63;
        const int row = blk * 4 + w;
        float4 a = *((const float4*)(x_re + (size_t)row * I_) + l);
        float4 c = *((const float4*)(x_im + (size_t)row * I_) + l);
        float sr = a.x*a.x + a.y*a.y + a.z*a.z + a.w*a.w;
        float si = c.x*c.x + c.y*c.y + c.z*c.z + c.w*c.w;
        #pragma unroll
        for (int off = 32; off > 0; off >>= 1) {
            sr += __shfl_down(sr, off);
            si += __shfl_down(si, off);
        }
        if (l == 0) { xsq_re[row] = sr; xsq_im[row] = si; }
    } else if (blk < 272) {
        const int l = t & 63, w = t >> 6;
        const int n = (blk - 256) * 64 + l;
        float sr = 0.f, si = 0.f;
        for (int i = w * 64; i < w * 64 + 64; ++i) {
            float g = G_re[(size_t)i * N_ + n]; sr += g * g;
            float h = G_im[(size_t)i * N_ + n]; si += h * h;
        }
        float (*red)[64] = (float(*)[64])smem;
        red[w][l] = sr; red[4 + w][l] = si;
        __syncthreads();
        if (w == 0) {
            gsq_re[n] = red[0][l] + red[1][l] + red[2][l] + red[3][l];
            gsq_im[n] = red[4][l] + red[5][l] + red[6][l] + red[7][l];
        }
    } else if (blk < 528) {
        // X -> frag order. 1024 tiles total (2 comps x 64 mt x 8 kt), 4/block.
        const int tile_lin = (blk - 272) * 4 + (t >> 6);
        const int comp = tile_lin >> 9;
        const int tl = tile_lin & 511;
        const int mt = tl >> 3, kt = tl & 7;
        const int lane = t & 63;
        const int quad = lane & 3, l16 = lane >> 2;   // read-coalescing map
        const float* src = (comp ? x_im : x_re)
                         + (size_t)(mt * 16 + l16) * I_ + kt * 32 + quad * 8;
        float4 a0 = *(const float4*)src;
        float4 a1 = *(const float4*)(src + 4);
        __align__(16) u16 tmp[8];
        tmp[0] = f2bf(a0.x); tmp[1] = f2bf(a0.y); tmp[2] = f2bf(a0.z); tmp[3] = f2bf(a0.w);
        tmp[4] = f2bf(a1.x); tmp[5] = f2bf(a1.y); tmp[6] = f2bf(a1.z); tmp[7] = f2bf(a1.w);
        u16* dst = (comp ? Xfi : Xfr)
                 + (size_t)(mt * 8 + kt) * 512 + (quad * 16 + l16) * 8;
        *(int4*)dst = *(const int4*)tmp;
    } else if (blk < 656) {
        const int local = blk - 528;
        const int comp = local >> 6, rem = local & 63;
        const int rt = rem >> 4, ct = rem & 15;   // 4 i-tiles x 16 n-tiles
        transconv_frag(comp ? G_im : G_re, comp ? GTfi : GTfr,
                       I_, N_, rt * 64, ct * 64, t, smem);
    } else {
        const int local = blk - 656;
        const int comp = local >> 6, rem = local & 63;
        const int rt = rem >> 2, ct = rem & 3;    // 16 n-tiles x 4 o-tiles
        transconv_frag(comp ? W_im : W_re, comp ? WTfi : WTfr,
                       N_, O_, rt * 64, ct * 64, t, smem);
    }
}

// ---------------------------------------------------------------------------
// phi GEMM (one comp per blockIdx.z): C = X @ G^T (K=256), frag-direct global
// loads (no staging LDS, no barriers in K-loop). Tile 64x64, 4 waves 2x2,
// each wave 32x32 via 2x2 fragments. Grid (16,16,2) = 512 blocks.
// Epilogue: v = xsq - 2C + gsq, phi = exp(-v/max(s,eps)); LDS transform to
// fragment order, coalesced b128 stores of P.
// ---------------------------------------------------------------------------
__global__ __launch_bounds__(256) void phi_mfma(
    const u16* __restrict__ Xfr, const u16* __restrict__ Xfi,
    const u16* __restrict__ GTfr, const u16* __restrict__ GTfi,
    const float* __restrict__ xsq_re, const float* __restrict__ xsq_im,
    const float* __restrict__ gsq_re, const float* __restrict__ gsq_im,
    const float* __restrict__ s_re, const float* __restrict__ s_im,
    u16* __restrict__ Pfr, u16* __restrict__ Pfi)
{
    __shared__ u16 pbuf[8 * 512];   // 8 KB: block's 64x64 P-chunk, frag order
    const int z = blockIdx.z;
    const u16* Xf  = z ? Xfi : Xfr;
    const u16* GTf = z ? GTfi : GTfr;
    const float* xsq = z ? xsq_im : xsq_re;
    const float* gsq = z ? gsq_im : gsq_re;
    const float* s   = z ? s_im : s_re;
    u16* Pf = z ? Pfi : Pfr;

    const int t = threadIdx.x;
    const int w = t >> 6, lane = t & 63;
    const int quad = lane >> 4, l16 = lane & 15;
    const int mw = (w >> 1) * 32, nw = (w & 1) * 32;
    const int mt0 = blockIdx.y * 4 + (mw >> 4);   // global 16-row tiles (X: 8 ktiles)
    const int nt0 = blockIdx.x * 4 + (nw >> 4);   // global 16-row tiles (GT: 8 ktiles)

    const u16* Ab = Xf  + lane * 8;
    const u16* Bb = GTf + lane * 8;

    f32x4 acc[2][2] = {};
    #pragma unroll
    for (int kt = 0; kt < 8; ++kt) {
        bf16x8 a0 = *(const bf16x8*)(Ab + (size_t)(mt0 * 8 + kt) * 512);
        bf16x8 a1 = *(const bf16x8*)(Ab + (size_t)((mt0 + 1) * 8 + kt) * 512);
        bf16x8 b0 = *(const bf16x8*)(Bb + (size_t)(nt0 * 8 + kt) * 512);
        bf16x8 b1 = *(const bf16x8*)(Bb + (size_t)((nt0 + 1) * 8 + kt) * 512);
        acc[0][0] = __builtin_amdgcn_mfma_f32_16x16x32_bf16(a0, b0, acc[0][0], 0, 0, 0);
        acc[0][1] = __builtin_amdgcn_mfma_f32_16x16x32_bf16(a0, b1, acc[0][1], 0, 0, 0);
        acc[1][0] = __builtin_amdgcn_mfma_f32_16x16x32_bf16(a1, b0, acc[1][0], 0, 0, 0);
        acc[1][1] = __builtin_amdgcn_mfma_f32_16x16x32_bf16(a1, b1, acc[1][1], 0, 0, 0);
    }

    // Epilogue into LDS in fragment order. C/D: col = lane&15, row = quad*4+r.
    const int m0 = blockIdx.y * 64, n0 = blockIdx.x * 64;
    #pragma unroll
    for (int mt = 0; mt < 2; ++mt)
        #pragma unroll
        for (int nt = 0; nt < 2; ++nt) {
            const int col = nw + nt * 16 + l16;            // local n in [0,64)
            const float gq = gsq[n0 + col];
            const float inv_s = 1.0f / fmaxf(s[n0 + col], EPSV);
            #pragma unroll
            for (int r = 0; r < 4; ++r) {
                const int row = mw + mt * 16 + quad * 4 + r;   // local m in [0,64)
                const float v = xsq[m0 + row] - 2.0f * acc[mt][nt][r] + gq;
                const u16 p = f2bf(__expf(-v * inv_s));
                const int lt = (row >> 4) * 2 + (col >> 5);
                pbuf[lt * 512 + (((col >> 3) & 3) * 16 + (row & 15)) * 8 + (col & 7)] = p;
            }
        }
    __syncthreads();

    // Coalesced copy LDS -> global frag-order P (P has N_/32 = 32 ktiles).
    const int lt = t >> 5, s32 = t & 31;
    const int mt_g = blockIdx.y * 4 + (lt >> 1);
    const int kt_g = blockIdx.x * 2 + (lt & 1);
    const u16* src = pbuf + lt * 512 + s32 * 16;
    u16* dst = Pf + (size_t)(mt_g * 32 + kt_g) * 512 + s32 * 16;
    *(int4*)dst = *(const int4*)src;
    *((int4*)dst + 1) = *((const int4*)src + 1);
}

// ---------------------------------------------------------------------------
// Complex GEMM, frag-direct, NO atomics, NO split-K dispatch:
//   y_re = Pr@Wr - Pi@Wi + b_re ; y_im = Pr@Wi + Pi@Wr + b_im  (K = 1024)
// 256 blocks (8 o-tiles x 32 b-tiles), 32x32 out per block; the 4 waves each
// reduce a K-quarter (256) with 2x2 complex fragments, then cross-wave LDS
// reduce + bias + coalesced float4 stores. Out written exactly once.
// ---------------------------------------------------------------------------
__global__ __launch_bounds__(256) void y_mfma(
    const u16* __restrict__ Pfr, const u16* __restrict__ Pfi,
    const u16* __restrict__ WTfr, const u16* __restrict__ WTfi,
    const float* __restrict__ b_re, const float* __restrict__ b_im,
    float* __restrict__ out)
{
    __shared__ float red[4][2][32][33];   // +1 pad: conflict-free scalar writes
    const int t = threadIdx.x;
    const int w = t >> 6, lane = t & 63;
    const int quad = lane >> 4, l16 = lane & 15;
    const int pm0 = blockIdx.y * 2;   // P 16-row tiles (32 ktiles)
    const int wo0 = blockIdx.x * 2;   // WT 16-row tiles (32 ktiles)

    const u16* Ar = Pfr + lane * 8;
    const u16* Ai = Pfi + lane * 8;
    const u16* Br = WTfr + lane * 8;
    const u16* Bi = WTfi + lane * 8;

    f32x4 cr[2][2] = {}, ci[2][2] = {};
    #pragma unroll
    for (int ks = 0; ks < 8; ++ks) {
        const int kt = w * 8 + ks;    // this wave's K-quarter
        bf16x8 ar[2], ai[2], an[2], br[2], bi[2];
        #pragma unroll
        for (int mt = 0; mt < 2; ++mt) {
            ar[mt] = *(const bf16x8*)(Ar + (size_t)((pm0 + mt) * 32 + kt) * 512);
            ai[mt] = *(const bf16x8*)(Ai + (size_t)((pm0 + mt) * 32 + kt) * 512);
            i32x4 tv = (*(const i32x4*)&ai[mt]) ^ 0x80008000;   // negate bf16 pairs
            an[mt] = *(const bf16x8*)&tv;
        }
        #pragma unroll
        for (int nt = 0; nt < 2; ++nt) {
            br[nt] = *(const bf16x8*)(Br + (size_t)((wo0 + nt) * 32 + kt) * 512);
            bi[nt] = *(const bf16x8*)(Bi + (size_t)((wo0 + nt) * 32 + kt) * 512);
        }
        #pragma unroll
        for (int mt = 0; mt < 2; ++mt)
            #pragma unroll
            for (int nt = 0; nt < 2; ++nt) {
                cr[mt][nt] = __builtin_amdgcn_mfma_f32_16x16x32_bf16(
                    ar[mt], br[nt], cr[mt][nt], 0, 0, 0);
                cr[mt][nt] = __builtin_amdgcn_mfma_f32_16x16x32_bf16(
                    an[mt], bi[nt], cr[mt][nt], 0, 0, 0);
                ci[mt][nt] = __builtin_amdgcn_mfma_f32_16x16x32_bf16(
                    ar[mt], bi[nt], ci[mt][nt], 0, 0, 0);
                ci[mt][nt] = __builtin_amdgcn_mfma_f32_16x16x32_bf16(
                    ai[mt], br[nt], ci[mt][nt], 0, 0, 0);
            }
    }

    // Cross-wave reduce. C/D: o = nt*16 + l16, b = mt*16 + quad*4 + r.
    #pragma unroll
    for (int mt = 0; mt < 2; ++mt)
        #pragma unroll
        for (int nt = 0; nt < 2; ++nt) {
            const int o = nt * 16 + l16;
            #pragma unroll
            for (int r = 0; r < 4; ++r) {
                const int b = mt * 16 + quad * 4 + r;
                red[w][0][b][o] = cr[mt][nt][r];
                red[w][1][b][o] = ci[mt][nt][r];
            }
        }
    __syncthreads();

    const int b = t >> 3, og = (t & 7) * 4;
    const int gb = blockIdx.y * 32 + b;
    #pragma unroll
    for (int p = 0; p < 2; ++p) {
        const int o = og + p * 2;
        const int go = blockIdx.x * 32 + o;
        float r0 = red[0][0][b][o]   + red[1][0][b][o]   + red[2][0][b][o]   + red[3][0][b][o];
        float i0 = red[0][1][b][o]   + red[1][1][b][o]   + red[2][1][b][o]   + red[3][1][b][o];
        float r1 = red[0][0][b][o+1] + red[1][0][b][o+1] + red[2][0][b][o+1] + red[3][0][b][o+1];
        float i1 = red[0][1][b][o+1] + red[1][1][b][o+1] + red[2][1][b][o+1] + red[3][1][b][o+1];
        float4 v;
        v.x = r0 + b_re[go];     v.y = i0 + b_im[go];
        v.z = r1 + b_re[go + 1]; v.w = i1 + b_im[go + 1];
        *(float4*)(out + ((size_t)gb * O_ + go) * 2) = v;
    }
}

extern "C" void kernel_launch(void* const* d_in, const int* in_sizes, int n_in,
                              void* d_out, int out_size, void* d_ws, size_t ws_size,
                              hipStream_t stream) {
    const float* x_re = (const float*)d_in[0];
    const float* x_im = (const float*)d_in[1];
    const float* G_re = (const float*)d_in[2];
    const float* G_im = (const float*)d_in[3];
    const float* s_re = (const float*)d_in[4];
    const float* s_im = (const float*)d_in[5];
    const float* W_re = (const float*)d_in[6];
    const float* W_im = (const float*)d_in[7];
    const float* b_re = (const float*)d_in[8];
    const float* b_im = (const float*)d_in[9];
    float* out = (float*)d_out;

    // Workspace layout (all frag-order bf16 unless noted)
    u16* Xfr  = (u16*)d_ws;                    // [B][I]  512 tiles
    u16* Xfi  = Xfr  + (size_t)B_ * I_;
    u16* GTfr = Xfi  + (size_t)B_ * I_;        // [N][I]  512 tiles
    u16* GTfi = GTfr + (size_t)N_ * I_;
    u16* WTfr = GTfi + (size_t)N_ * I_;        // [O][N]  512 tiles
    u16* WTfi = WTfr + (size_t)O_ * N_;
    u16* Pfr  = WTfi + (size_t)O_ * N_;        // [B][N]  2048 tiles
    u16* Pfi  = Pfr  + (size_t)B_ * N_;
    float* xsq_re = (float*)(Pfi + (size_t)B_ * N_);
    float* xsq_im = xsq_re + B_;
    float* gsq_re = xsq_im + B_;
    float* gsq_im = gsq_re + N_;

    prep_kernel<<<784, 256, 0, stream>>>(
        x_re, x_im, G_re, G_im, W_re, W_im,
        Xfr, Xfi, GTfr, GTfi, WTfr, WTfi,
        xsq_re, xsq_im, gsq_re, gsq_im);

    phi_mfma<<<dim3(N_ / 64, B_ / 64, 2), 256, 0, stream>>>(
        Xfr, Xfi, GTfr, GTfi, xsq_re, xsq_im, gsq_re, gsq_im,
        s_re, s_im, Pfr, Pfi);

    y_mfma<<<dim3(O_ / 32, B_ / 32), 256, 0, stream>>>(
        Pfr, Pfi, WTfr, WTfi, b_re, b_im, out);
}

// Round 7
// 95.749 us; speedup vs baseline: 4.6100x; 1.0463x over previous
//
#include <hip/hip_runtime.h>
#include <math.h>

#define B_ 1024
#define I_ 256
#define N_ 1024
#define O_ 256
#define EPSV 1e-5f

typedef unsigned short u16;
typedef short bf16x8 __attribute__((ext_vector_type(8)));   // 8 bf16 = 4 VGPRs
typedef float f32x4 __attribute__((ext_vector_type(4)));
typedef int i32x4 __attribute__((ext_vector_type(4)));

__device__ inline u16 f2bf(float f) {
    union { float f; unsigned int u; } v; v.f = f;
    unsigned int r = v.u + 0x7FFFu + ((v.u >> 16) & 1u);   // round-to-nearest-even
    return (u16)(r >> 16);
}

// Fragment-order storage: per (row16-tile, k32-tile) store 64 chunks of 8 bf16.
// chunk slot = quad*16 + (row&15); matches MFMA A/B layout
// (m|n = lane&15, k = (lane>>4)*8 + j). Tile = 512 u16 = 1 KB.

__device__ inline void transconv_frag(const float* __restrict__ in,
                                      u16* __restrict__ out, int R, int C,
                                      int r0, int c0, int t, float (*tile)[69]) {
    const int lr = t >> 2, lq = t & 3;
    #pragma unroll
    for (int j = 0; j < 4; ++j) {
        float4 v = *(const float4*)(in + (size_t)(r0 + lr) * C + c0 + lq * 16 + j * 4);
        *(float4*)&tile[lr][lq * 16 + j * 4] = v;
    }
    __syncthreads();
    const int oc = t >> 2, oq = t & 3;
    const int row = c0 + oc;
    const int ktiles = R >> 5;
    #pragma unroll
    for (int h = 0; h < 2; ++h) {
        const int k0 = r0 + oq * 16 + h * 8;
        const int kt = k0 >> 5, quad = (k0 >> 3) & 3;
        __align__(16) u16 tmp[8];
        #pragma unroll
        for (int e = 0; e < 8; ++e)
            tmp[e] = f2bf(tile[oq * 16 + h * 8 + e][oc]);
        const size_t off = ((size_t)((row >> 4) * ktiles + kt)) * 512
                         + (quad * 16 + (row & 15)) * 8;
        *(int4*)(out + off) = *(const int4*)tmp;
    }
}

// ---------------------------------------------------------------------------
// Fused prep (784 blocks): xsq | gsq | X->frag | GT->frag | WT->frag
// ---------------------------------------------------------------------------
__global__ __launch_bounds__(256) void prep_kernel(
    const float* __restrict__ x_re, const float* __restrict__ x_im,
    const float* __restrict__ G_re, const float* __restrict__ G_im,
    const float* __restrict__ W_re, const float* __restrict__ W_im,
    u16* __restrict__ Xfr, u16* __restrict__ Xfi,
    u16* __restrict__ GTfr, u16* __restrict__ GTfi,
    u16* __restrict__ WTfr, u16* __restrict__ WTfi,
    float* __restrict__ xsq_re, float* __restrict__ xsq_im,
    float* __restrict__ gsq_re, float* __restrict__ gsq_im)
{
    __shared__ float smem[64][69];
    const int blk = blockIdx.x, t = threadIdx.x;

    if (blk < 256) {
        const int w = t >> 6, l = t & 63;
        const int row = blk * 4 + w;
        float4 a = *((const float4*)(x_re + (size_t)row * I_) + l);
        float4 c = *((const float4*)(x_im + (size_t)row * I_) + l);
        float sr = a.x*a.x + a.y*a.y + a.z*a.z + a.w*a.w;
        float si = c.x*c.x + c.y*c.y + c.z*c.z + c.w*c.w;
        #pragma unroll
        for (int off = 32; off > 0; off >>= 1) {
            sr += __shfl_down(sr, off);
            si += __shfl_down(si, off);
        }
        if (l == 0) { xsq_re[row] = sr; xsq_im[row] = si; }
    } else if (blk < 272) {
        const int l = t & 63, w = t >> 6;
        const int n = (blk - 256) * 64 + l;
        float sr = 0.f, si = 0.f;
        for (int i = w * 64; i < w * 64 + 64; ++i) {
            float g = G_re[(size_t)i * N_ + n]; sr += g * g;
            float h = G_im[(size_t)i * N_ + n]; si += h * h;
        }
        float (*red)[64] = (float(*)[64])smem;
        red[w][l] = sr; red[4 + w][l] = si;
        __syncthreads();
        if (w == 0) {
            gsq_re[n] = red[0][l] + red[1][l] + red[2][l] + red[3][l];
            gsq_im[n] = red[4][l] + red[5][l] + red[6][l] + red[7][l];
        }
    } else if (blk < 528) {
        const int tile_lin = (blk - 272) * 4 + (t >> 6);
        const int comp = tile_lin >> 9;
        const int tl = tile_lin & 511;
        const int mt = tl >> 3, kt = tl & 7;
        const int lane = t & 63;
        const int quad = lane & 3, l16 = lane >> 2;
        const float* src = (comp ? x_im : x_re)
                         + (size_t)(mt * 16 + l16) * I_ + kt * 32 + quad * 8;
        float4 a0 = *(const float4*)src;
        float4 a1 = *(const float4*)(src + 4);
        __align__(16) u16 tmp[8];
        tmp[0] = f2bf(a0.x); tmp[1] = f2bf(a0.y); tmp[2] = f2bf(a0.z); tmp[3] = f2bf(a0.w);
        tmp[4] = f2bf(a1.x); tmp[5] = f2bf(a1.y); tmp[6] = f2bf(a1.z); tmp[7] = f2bf(a1.w);
        u16* dst = (comp ? Xfi : Xfr)
                 + (size_t)(mt * 8 + kt) * 512 + (quad * 16 + l16) * 8;
        *(int4*)dst = *(const int4*)tmp;
    } else if (blk < 656) {
        const int local = blk - 528;
        const int comp = local >> 6, rem = local & 63;
        const int rt = rem >> 4, ct = rem & 15;
        transconv_frag(comp ? G_im : G_re, comp ? GTfi : GTfr,
                       I_, N_, rt * 64, ct * 64, t, smem);
    } else {
        const int local = blk - 656;
        const int comp = local >> 6, rem = local & 63;
        const int rt = rem >> 2, ct = rem & 3;
        transconv_frag(comp ? W_im : W_re, comp ? WTfi : WTfr,
                       N_, O_, rt * 64, ct * 64, t, smem);
    }
}

// ---------------------------------------------------------------------------
// phi GEMM (comp per blockIdx.z): C = X @ G^T (K=256), frag-direct loads with
// explicit register prefetch (no LDS in K-loop). Tile 64x64, 4 waves 2x2.
// Grid (16,16,2) = 512. Epilogue -> frag-order P via 8 KB LDS + b128 stores.
// ---------------------------------------------------------------------------
__global__ __launch_bounds__(256) void phi_mfma(
    const u16* __restrict__ Xfr, const u16* __restrict__ Xfi,
    const u16* __restrict__ GTfr, const u16* __restrict__ GTfi,
    const float* __restrict__ xsq_re, const float* __restrict__ xsq_im,
    const float* __restrict__ gsq_re, const float* __restrict__ gsq_im,
    const float* __restrict__ s_re, const float* __restrict__ s_im,
    u16* __restrict__ Pfr, u16* __restrict__ Pfi)
{
    __shared__ u16 pbuf[8 * 512];
    const int z = blockIdx.z;
    const u16* Xf  = z ? Xfi : Xfr;
    const u16* GTf = z ? GTfi : GTfr;
    const float* xsq = z ? xsq_im : xsq_re;
    const float* gsq = z ? gsq_im : gsq_re;
    const float* s   = z ? s_im : s_re;
    u16* Pf = z ? Pfi : Pfr;

    const int t = threadIdx.x;
    const int w = t >> 6, lane = t & 63;
    const int quad = lane >> 4, l16 = lane & 15;
    const int mw = (w >> 1) * 32, nw = (w & 1) * 32;
    const int mt0 = blockIdx.y * 4 + (mw >> 4);
    const int nt0 = blockIdx.x * 4 + (nw >> 4);

    const u16* Ab = Xf  + lane * 8;
    const u16* Bb = GTf + lane * 8;
    const size_t a0o = (size_t)(mt0 * 8) * 512;
    const size_t a1o = (size_t)((mt0 + 1) * 8) * 512;
    const size_t b0o = (size_t)(nt0 * 8) * 512;
    const size_t b1o = (size_t)((nt0 + 1) * 8) * 512;

    bf16x8 cA0 = *(const bf16x8*)(Ab + a0o);
    bf16x8 cA1 = *(const bf16x8*)(Ab + a1o);
    bf16x8 cB0 = *(const bf16x8*)(Bb + b0o);
    bf16x8 cB1 = *(const bf16x8*)(Bb + b1o);

    f32x4 acc[2][2] = {};
    #pragma unroll
    for (int kt = 0; kt < 8; ++kt) {
        bf16x8 nA0, nA1, nB0, nB1;
        if (kt < 7) {
            const size_t ko = (size_t)(kt + 1) * 512;
            nA0 = *(const bf16x8*)(Ab + a0o + ko);
            nA1 = *(const bf16x8*)(Ab + a1o + ko);
            nB0 = *(const bf16x8*)(Bb + b0o + ko);
            nB1 = *(const bf16x8*)(Bb + b1o + ko);
        }
        acc[0][0] = __builtin_amdgcn_mfma_f32_16x16x32_bf16(cA0, cB0, acc[0][0], 0, 0, 0);
        acc[0][1] = __builtin_amdgcn_mfma_f32_16x16x32_bf16(cA0, cB1, acc[0][1], 0, 0, 0);
        acc[1][0] = __builtin_amdgcn_mfma_f32_16x16x32_bf16(cA1, cB0, acc[1][0], 0, 0, 0);
        acc[1][1] = __builtin_amdgcn_mfma_f32_16x16x32_bf16(cA1, cB1, acc[1][1], 0, 0, 0);
        cA0 = nA0; cA1 = nA1; cB0 = nB0; cB1 = nB1;
    }

    // Epilogue into LDS in fragment order. C/D: col = lane&15, row = quad*4+r.
    const int m0 = blockIdx.y * 64, n0 = blockIdx.x * 64;
    #pragma unroll
    for (int mt = 0; mt < 2; ++mt)
        #pragma unroll
        for (int nt = 0; nt < 2; ++nt) {
            const int col = nw + nt * 16 + l16;
            const float gq = gsq[n0 + col];
            const float inv_s = 1.0f / fmaxf(s[n0 + col], EPSV);
            #pragma unroll
            for (int r = 0; r < 4; ++r) {
                const int row = mw + mt * 16 + quad * 4 + r;
                const float v = xsq[m0 + row] - 2.0f * acc[mt][nt][r] + gq;
                const u16 p = f2bf(__expf(-v * inv_s));
                const int lt = (row >> 4) * 2 + (col >> 5);
                pbuf[lt * 512 + (((col >> 3) & 3) * 16 + (row & 15)) * 8 + (col & 7)] = p;
            }
        }
    __syncthreads();

    const int lt = t >> 5, s32 = t & 31;
    const int mt_g = blockIdx.y * 4 + (lt >> 1);
    const int kt_g = blockIdx.x * 2 + (lt & 1);
    const u16* src = pbuf + lt * 512 + s32 * 16;
    u16* dst = Pf + (size_t)(mt_g * 32 + kt_g) * 512 + s32 * 16;
    *(int4*)dst = *(const int4*)src;
    *((int4*)dst + 1) = *((const int4*)src + 1);
}

// ---------------------------------------------------------------------------
// Complex GEMM, frag-direct, no atomics. Grid (8, 64) = 512 blocks
// (2 blocks/CU): each block 16(b) x 32(o); 4 waves each reduce a K-quarter
// (256) with 1x2 complex fragments + register prefetch; LDS cross-wave
// reduce (pad 34 -> <=2-way banks) + bias + coalesced float4 stores.
// ---------------------------------------------------------------------------
__global__ __launch_bounds__(256) void y_mfma(
    const u16* __restrict__ Pfr, const u16* __restrict__ Pfi,
    const u16* __restrict__ WTfr, const u16* __restrict__ WTfi,
    const float* __restrict__ b_re, const float* __restrict__ b_im,
    float* __restrict__ out)
{
    __shared__ float red[4][2][16][34];
    const int t = threadIdx.x;
    const int w = t >> 6, lane = t & 63;
    const int quad = lane >> 4, l16 = lane & 15;
    const int pm = blockIdx.y;        // P 16-row tile (32 ktiles)
    const int wo0 = blockIdx.x * 2;   // WT 16-row tiles

    const u16* Ar = Pfr + lane * 8;
    const u16* Ai = Pfi + lane * 8;
    const u16* Br = WTfr + lane * 8;
    const u16* Bi = WTfi + lane * 8;
    const size_t ao = (size_t)(pm * 32 + w * 8) * 512;
    const size_t b0o = (size_t)(wo0 * 32 + w * 8) * 512;
    const size_t b1o = (size_t)((wo0 + 1) * 32 + w * 8) * 512;

    bf16x8 cAr = *(const bf16x8*)(Ar + ao);
    bf16x8 cAi = *(const bf16x8*)(Ai + ao);
    bf16x8 cBr0 = *(const bf16x8*)(Br + b0o);
    bf16x8 cBi0 = *(const bf16x8*)(Bi + b0o);
    bf16x8 cBr1 = *(const bf16x8*)(Br + b1o);
    bf16x8 cBi1 = *(const bf16x8*)(Bi + b1o);

    f32x4 cr[2] = {}, ci[2] = {};
    #pragma unroll
    for (int ks = 0; ks < 8; ++ks) {
        bf16x8 nAr, nAi, nBr0, nBi0, nBr1, nBi1;
        if (ks < 7) {
            const size_t ko = (size_t)(ks + 1) * 512;
            nAr  = *(const bf16x8*)(Ar + ao + ko);
            nAi  = *(const bf16x8*)(Ai + ao + ko);
            nBr0 = *(const bf16x8*)(Br + b0o + ko);
            nBi0 = *(const bf16x8*)(Bi + b0o + ko);
            nBr1 = *(const bf16x8*)(Br + b1o + ko);
            nBi1 = *(const bf16x8*)(Bi + b1o + ko);
        }
        i32x4 tv = (*(const i32x4*)&cAi) ^ 0x80008000;   // negate bf16 pairs
        bf16x8 cAn = *(const bf16x8*)&tv;
        cr[0] = __builtin_amdgcn_mfma_f32_16x16x32_bf16(cAr, cBr0, cr[0], 0, 0, 0);
        cr[0] = __builtin_amdgcn_mfma_f32_16x16x32_bf16(cAn, cBi0, cr[0], 0, 0, 0);
        ci[0] = __builtin_amdgcn_mfma_f32_16x16x32_bf16(cAr, cBi0, ci[0], 0, 0, 0);
        ci[0] = __builtin_amdgcn_mfma_f32_16x16x32_bf16(cAi, cBr0, ci[0], 0, 0, 0);
        cr[1] = __builtin_amdgcn_mfma_f32_16x16x32_bf16(cAr, cBr1, cr[1], 0, 0, 0);
        cr[1] = __builtin_amdgcn_mfma_f32_16x16x32_bf16(cAn, cBi1, cr[1], 0, 0, 0);
        ci[1] = __builtin_amdgcn_mfma_f32_16x16x32_bf16(cAr, cBi1, ci[1], 0, 0, 0);
        ci[1] = __builtin_amdgcn_mfma_f32_16x16x32_bf16(cAi, cBr1, ci[1], 0, 0, 0);
        cAr = nAr; cAi = nAi;
        cBr0 = nBr0; cBi0 = nBi0; cBr1 = nBr1; cBi1 = nBi1;
    }

    // C/D: o_local = nt*16 + l16, b_local = quad*4 + r.
    #pragma unroll
    for (int nt = 0; nt < 2; ++nt) {
        const int o = nt * 16 + l16;
        #pragma unroll
        for (int r = 0; r < 4; ++r) {
            const int b = quad * 4 + r;
            red[w][0][b][o] = cr[nt][r];
            red[w][1][b][o] = ci[nt][r];
        }
    }
    __syncthreads();

    const int b = t >> 4, oq = t & 15;
    const int o = oq * 2;
    const int gb = blockIdx.y * 16 + b;
    const int go = blockIdx.x * 32 + o;
    float r0 = red[0][0][b][o]   + red[1][0][b][o]   + red[2][0][b][o]   + red[3][0][b][o];
    float i0 = red[0][1][b][o]   + red[1][1][b][o]   + red[2][1][b][o]   + red[3][1][b][o];
    float r1 = red[0][0][b][o+1] + red[1][0][b][o+1] + red[2][0][b][o+1] + red[3][0][b][o+1];
    float i1 = red[0][1][b][o+1] + red[1][1][b][o+1] + red[2][1][b][o+1] + red[3][1][b][o+1];
    float4 v;
    v.x = r0 + b_re[go];     v.y = i0 + b_im[go];
    v.z = r1 + b_re[go + 1]; v.w = i1 + b_im[go + 1];
    *(float4*)(out + ((size_t)gb * O_ + go) * 2) = v;
}

extern "C" void kernel_launch(void* const* d_in, const int* in_sizes, int n_in,
                              void* d_out, int out_size, void* d_ws, size_t ws_size,
                              hipStream_t stream) {
    const float* x_re = (const float*)d_in[0];
    const float* x_im = (const float*)d_in[1];
    const float* G_re = (const float*)d_in[2];
    const float* G_im = (const float*)d_in[3];
    const float* s_re = (const float*)d_in[4];
    const float* s_im = (const float*)d_in[5];
    const float* W_re = (const float*)d_in[6];
    const float* W_im = (const float*)d_in[7];
    const float* b_re = (const float*)d_in[8];
    const float* b_im = (const float*)d_in[9];
    float* out = (float*)d_out;

    u16* Xfr  = (u16*)d_ws;
    u16* Xfi  = Xfr  + (size_t)B_ * I_;
    u16* GTfr = Xfi  + (size_t)B_ * I_;
    u16* GTfi = GTfr + (size_t)N_ * I_;
    u16* WTfr = GTfi + (size_t)N_ * I_;
    u16* WTfi = WTfr + (size_t)O_ * N_;
    u16* Pfr  = WTfi + (size_t)O_ * N_;
    u16* Pfi  = Pfr  + (size_t)B_ * N_;
    float* xsq_re = (float*)(Pfi + (size_t)B_ * N_);
    float* xsq_im = xsq_re + B_;
    float* gsq_re = xsq_im + B_;
    float* gsq_im = gsq_re + N_;

    prep_kernel<<<784, 256, 0, stream>>>(
        x_re, x_im, G_re, G_im, W_re, W_im,
        Xfr, Xfi, GTfr, GTfi, WTfr, WTfi,
        xsq_re, xsq_im, gsq_re, gsq_im);

    phi_mfma<<<dim3(N_ / 64, B_ / 64, 2), 256, 0, stream>>>(
        Xfr, Xfi, GTfr, GTfi, xsq_re, xsq_im, gsq_re, gsq_im,
        s_re, s_im, Pfr, Pfi);

    y_mfma<<<dim3(O_ / 32, B_ / 16), 256, 0, stream>>>(
        Pfr, Pfi, WTfr, WTfi, b_re, b_im, out);
}

// Round 8
// 90.444 us; speedup vs baseline: 4.8804x; 1.0587x over previous
//
#include <hip/hip_runtime.h>
#include <math.h>

#define B_ 1024
#define I_ 256
#define N_ 1024
#define O_ 256
#define EPSV 1e-5f

typedef unsigned short u16;
typedef short bf16x8 __attribute__((ext_vector_type(8)));   // 8 bf16 = 4 VGPRs
typedef float f32x4 __attribute__((ext_vector_type(4)));
typedef int i32x4 __attribute__((ext_vector_type(4)));

__device__ inline u16 f2bf(float f) {
    union { float f; unsigned int u; } v; v.f = f;
    unsigned int r = v.u + 0x7FFFu + ((v.u >> 16) & 1u);   // round-to-nearest-even
    return (u16)(r >> 16);
}

// Fragment-order storage: per (row16-tile, k32-tile) store 64 chunks of 8 bf16.
// chunk slot = quad*16 + (row&15) = lane; matches MFMA A/B layout
// (m|n = lane&15, k = (lane>>4)*8 + j). Tile = 512 u16 = 1 KB.

// ---------------------------------------------------------------------------
// Transpose + convert into fragment order; optionally accumulate column
// sum-of-squares partials into gpart[(r0/64)*N + col] (one write per col/tile,
// no atomics; gpart layout [R/64][C]).
// ---------------------------------------------------------------------------
__device__ inline void transconv_frag(const float* __restrict__ in,
                                      u16* __restrict__ out, int R, int C,
                                      int r0, int c0, int t, float (*tile)[69],
                                      float* __restrict__ gpart) {
    const int lr = t >> 2, lq = t & 3;
    #pragma unroll
    for (int j = 0; j < 4; ++j) {
        float4 v = *(const float4*)(in + (size_t)(r0 + lr) * C + c0 + lq * 16 + j * 4);
        *(float4*)&tile[lr][lq * 16 + j * 4] = v;
    }
    __syncthreads();
    const int oc = t >> 2, oq = t & 3;
    const int row = c0 + oc;
    const int ktiles = R >> 5;
    float ss = 0.f;
    #pragma unroll
    for (int h = 0; h < 2; ++h) {
        const int k0 = r0 + oq * 16 + h * 8;
        const int kt = k0 >> 5, quad = (k0 >> 3) & 3;
        __align__(16) u16 tmp[8];
        #pragma unroll
        for (int e = 0; e < 8; ++e) {
            const float g = tile[oq * 16 + h * 8 + e][oc];
            ss += g * g;
            tmp[e] = f2bf(g);
        }
        const size_t off = ((size_t)((row >> 4) * ktiles + kt)) * 512
                         + (quad * 16 + (row & 15)) * 8;
        *(int4*)(out + off) = *(const int4*)tmp;
    }
    if (gpart) {
        // threads t = oc*4 + oq: reduce over oq (lanes differ in low 2 bits)
        ss += __shfl_xor(ss, 1);
        ss += __shfl_xor(ss, 2);
        if (oq == 0) gpart[(r0 >> 6) * C + row] = ss;
    }
}

// ---------------------------------------------------------------------------
// Fused prep, 288 uniform blocks:
//   [0,32):    X fp32 -> frag bf16 + xsq (1 wave per (comp, 16-row tile))
//   [32,160):  G [I][N] -> GT frag + gsq partials [4][N]
//   [160,288): W [N][O] -> WT frag
// ---------------------------------------------------------------------------
__global__ __launch_bounds__(256) void prep_kernel(
    const float* __restrict__ x_re, const float* __restrict__ x_im,
    const float* __restrict__ G_re, const float* __restrict__ G_im,
    const float* __restrict__ W_re, const float* __restrict__ W_im,
    u16* __restrict__ Xfr, u16* __restrict__ Xfi,
    u16* __restrict__ GTfr, u16* __restrict__ GTfi,
    u16* __restrict__ WTfr, u16* __restrict__ WTfi,
    float* __restrict__ xsq_re, float* __restrict__ xsq_im,
    float* __restrict__ gsq_re_part, float* __restrict__ gsq_im_part)
{
    __shared__ float smem[64][69];
    const int blk = blockIdx.x, t = threadIdx.x;

    if (blk < 32) {
        const int unit = blk * 4 + (t >> 6);     // [0,128): comp x 64 m-tiles
        const int comp = unit >> 6, mt = unit & 63;
        const int lane = t & 63;
        const int l16 = lane & 15, quad = lane >> 4;
        const float* src = (comp ? x_im : x_re)
                         + (size_t)(mt * 16 + l16) * I_ + quad * 8;
        u16* dstbase = (comp ? Xfi : Xfr) + (size_t)(mt * 8) * 512 + lane * 8;
        float ssum = 0.f;
        #pragma unroll
        for (int kt = 0; kt < 8; ++kt) {
            float4 a0 = *(const float4*)(src + kt * 32);
            float4 a1 = *(const float4*)(src + kt * 32 + 4);
            ssum += a0.x*a0.x + a0.y*a0.y + a0.z*a0.z + a0.w*a0.w
                  + a1.x*a1.x + a1.y*a1.y + a1.z*a1.z + a1.w*a1.w;
            __align__(16) u16 tmp[8];
            tmp[0] = f2bf(a0.x); tmp[1] = f2bf(a0.y);
            tmp[2] = f2bf(a0.z); tmp[3] = f2bf(a0.w);
            tmp[4] = f2bf(a1.x); tmp[5] = f2bf(a1.y);
            tmp[6] = f2bf(a1.z); tmp[7] = f2bf(a1.w);
            *(int4*)(dstbase + (size_t)kt * 512) = *(const int4*)tmp;
        }
        // row r partials live in lanes r, r+16, r+32, r+48
        ssum += __shfl_xor(ssum, 16);
        ssum += __shfl_xor(ssum, 32);
        if (lane < 16) {
            float* xsq = comp ? xsq_im : xsq_re;
            xsq[mt * 16 + lane] = ssum;
        }
    } else if (blk < 160) {
        const int local = blk - 32;
        const int comp = local >> 6, rem = local & 63;
        const int rt = rem >> 4, ct = rem & 15;   // 4 i-tiles x 16 n-tiles
        transconv_frag(comp ? G_im : G_re, comp ? GTfi : GTfr,
                       I_, N_, rt * 64, ct * 64, t, smem,
                       comp ? gsq_im_part : gsq_re_part);
    } else {
        const int local = blk - 160;
        const int comp = local >> 6, rem = local & 63;
        const int rt = rem >> 2, ct = rem & 3;    // 16 n-tiles x 4 o-tiles
        transconv_frag(comp ? W_im : W_re, comp ? WTfi : WTfr,
                       N_, O_, rt * 64, ct * 64, t, smem, (float*)0);
    }
}

// ---------------------------------------------------------------------------
// phi GEMM (comp per blockIdx.z): C = X @ G^T (K=256), frag-direct loads with
// register prefetch (no LDS in K-loop). Tile 64x64, 4 waves 2x2.
// Grid (16,16,2) = 512. Epilogue -> frag-order P via 8 KB LDS + b128 stores.
// gsq comes as 4 partials [4][N].
// ---------------------------------------------------------------------------
__global__ __launch_bounds__(256) void phi_mfma(
    const u16* __restrict__ Xfr, const u16* __restrict__ Xfi,
    const u16* __restrict__ GTfr, const u16* __restrict__ GTfi,
    const float* __restrict__ xsq_re, const float* __restrict__ xsq_im,
    const float* __restrict__ gsq_re_part, const float* __restrict__ gsq_im_part,
    const float* __restrict__ s_re, const float* __restrict__ s_im,
    u16* __restrict__ Pfr, u16* __restrict__ Pfi)
{
    __shared__ u16 pbuf[8 * 512];
    const int z = blockIdx.z;
    const u16* Xf  = z ? Xfi : Xfr;
    const u16* GTf = z ? GTfi : GTfr;
    const float* xsq = z ? xsq_im : xsq_re;
    const float* gp  = z ? gsq_im_part : gsq_re_part;
    const float* s   = z ? s_im : s_re;
    u16* Pf = z ? Pfi : Pfr;

    const int t = threadIdx.x;
    const int w = t >> 6, lane = t & 63;
    const int quad = lane >> 4, l16 = lane & 15;
    const int mw = (w >> 1) * 32, nw = (w & 1) * 32;
    const int mt0 = blockIdx.y * 4 + (mw >> 4);
    const int nt0 = blockIdx.x * 4 + (nw >> 4);

    const u16* Ab = Xf  + lane * 8;
    const u16* Bb = GTf + lane * 8;
    const size_t a0o = (size_t)(mt0 * 8) * 512;
    const size_t a1o = (size_t)((mt0 + 1) * 8) * 512;
    const size_t b0o = (size_t)(nt0 * 8) * 512;
    const size_t b1o = (size_t)((nt0 + 1) * 8) * 512;

    bf16x8 cA0 = *(const bf16x8*)(Ab + a0o);
    bf16x8 cA1 = *(const bf16x8*)(Ab + a1o);
    bf16x8 cB0 = *(const bf16x8*)(Bb + b0o);
    bf16x8 cB1 = *(const bf16x8*)(Bb + b1o);

    f32x4 acc[2][2] = {};
    #pragma unroll
    for (int kt = 0; kt < 8; ++kt) {
        bf16x8 nA0, nA1, nB0, nB1;
        if (kt < 7) {
            const size_t ko = (size_t)(kt + 1) * 512;
            nA0 = *(const bf16x8*)(Ab + a0o + ko);
            nA1 = *(const bf16x8*)(Ab + a1o + ko);
            nB0 = *(const bf16x8*)(Bb + b0o + ko);
            nB1 = *(const bf16x8*)(Bb + b1o + ko);
        }
        acc[0][0] = __builtin_amdgcn_mfma_f32_16x16x32_bf16(cA0, cB0, acc[0][0], 0, 0, 0);
        acc[0][1] = __builtin_amdgcn_mfma_f32_16x16x32_bf16(cA0, cB1, acc[0][1], 0, 0, 0);
        acc[1][0] = __builtin_amdgcn_mfma_f32_16x16x32_bf16(cA1, cB0, acc[1][0], 0, 0, 0);
        acc[1][1] = __builtin_amdgcn_mfma_f32_16x16x32_bf16(cA1, cB1, acc[1][1], 0, 0, 0);
        cA0 = nA0; cA1 = nA1; cB0 = nB0; cB1 = nB1;
    }

    // Epilogue into LDS in fragment order. C/D: col = lane&15, row = quad*4+r.
    const int m0 = blockIdx.y * 64, n0 = blockIdx.x * 64;
    #pragma unroll
    for (int mt = 0; mt < 2; ++mt)
        #pragma unroll
        for (int nt = 0; nt < 2; ++nt) {
            const int col = nw + nt * 16 + l16;
            const int gn = n0 + col;
            const float gq = gp[gn] + gp[N_ + gn] + gp[2 * N_ + gn] + gp[3 * N_ + gn];
            const float inv_s = 1.0f / fmaxf(s[gn], EPSV);
            #pragma unroll
            for (int r = 0; r < 4; ++r) {
                const int row = mw + mt * 16 + quad * 4 + r;
                const float v = xsq[m0 + row] - 2.0f * acc[mt][nt][r] + gq;
                const u16 p = f2bf(__expf(-v * inv_s));
                const int lt = (row >> 4) * 2 + (col >> 5);
                pbuf[lt * 512 + (((col >> 3) & 3) * 16 + (row & 15)) * 8 + (col & 7)] = p;
            }
        }
    __syncthreads();

    const int lt = t >> 5, s32 = t & 31;
    const int mt_g = blockIdx.y * 4 + (lt >> 1);
    const int kt_g = blockIdx.x * 2 + (lt & 1);
    const u16* src = pbuf + lt * 512 + s32 * 16;
    u16* dst = Pf + (size_t)(mt_g * 32 + kt_g) * 512 + s32 * 16;
    *(int4*)dst = *(const int4*)src;
    *((int4*)dst + 1) = *((const int4*)src + 1);
}

// ---------------------------------------------------------------------------
// Complex GEMM, frag-direct, no atomics. Grid (8, 64) = 512 blocks
// (2 blocks/CU): each block 16(b) x 32(o); 4 waves each reduce a K-quarter
// (256) with 1x2 complex fragments + register prefetch; LDS cross-wave
// reduce + bias + coalesced float4 stores.
// ---------------------------------------------------------------------------
__global__ __launch_bounds__(256) void y_mfma(
    const u16* __restrict__ Pfr, const u16* __restrict__ Pfi,
    const u16* __restrict__ WTfr, const u16* __restrict__ WTfi,
    const float* __restrict__ b_re, const float* __restrict__ b_im,
    float* __restrict__ out)
{
    __shared__ float red[4][2][16][34];
    const int t = threadIdx.x;
    const int w = t >> 6, lane = t & 63;
    const int quad = lane >> 4, l16 = lane & 15;
    const int pm = blockIdx.y;        // P 16-row tile (32 ktiles)
    const int wo0 = blockIdx.x * 2;   // WT 16-row tiles

    const u16* Ar = Pfr + lane * 8;
    const u16* Ai = Pfi + lane * 8;
    const u16* Br = WTfr + lane * 8;
    const u16* Bi = WTfi + lane * 8;
    const size_t ao = (size_t)(pm * 32 + w * 8) * 512;
    const size_t b0o = (size_t)(wo0 * 32 + w * 8) * 512;
    const size_t b1o = (size_t)((wo0 + 1) * 32 + w * 8) * 512;

    bf16x8 cAr = *(const bf16x8*)(Ar + ao);
    bf16x8 cAi = *(const bf16x8*)(Ai + ao);
    bf16x8 cBr0 = *(const bf16x8*)(Br + b0o);
    bf16x8 cBi0 = *(const bf16x8*)(Bi + b0o);
    bf16x8 cBr1 = *(const bf16x8*)(Br + b1o);
    bf16x8 cBi1 = *(const bf16x8*)(Bi + b1o);

    f32x4 cr[2] = {}, ci[2] = {};
    #pragma unroll
    for (int ks = 0; ks < 8; ++ks) {
        bf16x8 nAr, nAi, nBr0, nBi0, nBr1, nBi1;
        if (ks < 7) {
            const size_t ko = (size_t)(ks + 1) * 512;
            nAr  = *(const bf16x8*)(Ar + ao + ko);
            nAi  = *(const bf16x8*)(Ai + ao + ko);
            nBr0 = *(const bf16x8*)(Br + b0o + ko);
            nBi0 = *(const bf16x8*)(Bi + b0o + ko);
            nBr1 = *(const bf16x8*)(Br + b1o + ko);
            nBi1 = *(const bf16x8*)(Bi + b1o + ko);
        }
        i32x4 tv = (*(const i32x4*)&cAi) ^ 0x80008000;   // negate bf16 pairs
        bf16x8 cAn = *(const bf16x8*)&tv;
        cr[0] = __builtin_amdgcn_mfma_f32_16x16x32_bf16(cAr, cBr0, cr[0], 0, 0, 0);
        cr[0] = __builtin_amdgcn_mfma_f32_16x16x32_bf16(cAn, cBi0, cr[0], 0, 0, 0);
        ci[0] = __builtin_amdgcn_mfma_f32_16x16x32_bf16(cAr, cBi0, ci[0], 0, 0, 0);
        ci[0] = __builtin_amdgcn_mfma_f32_16x16x32_bf16(cAi, cBr0, ci[0], 0, 0, 0);
        cr[1] = __builtin_amdgcn_mfma_f32_16x16x32_bf16(cAr, cBr1, cr[1], 0, 0, 0);
        cr[1] = __builtin_amdgcn_mfma_f32_16x16x32_bf16(cAn, cBi1, cr[1], 0, 0, 0);
        ci[1] = __builtin_amdgcn_mfma_f32_16x16x32_bf16(cAr, cBi1, ci[1], 0, 0, 0);
        ci[1] = __builtin_amdgcn_mfma_f32_16x16x32_bf16(cAi, cBr1, ci[1], 0, 0, 0);
        cAr = nAr; cAi = nAi;
        cBr0 = nBr0; cBi0 = nBi0; cBr1 = nBr1; cBi1 = nBi1;
    }

    // C/D: o_local = nt*16 + l16, b_local = quad*4 + r.
    #pragma unroll
    for (int nt = 0; nt < 2; ++nt) {
        const int o = nt * 16 + l16;
        #pragma unroll
        for (int r = 0; r < 4; ++r) {
            const int b = quad * 4 + r;
            red[w][0][b][o] = cr[nt][r];
            red[w][1][b][o] = ci[nt][r];
        }
    }
    __syncthreads();

    const int b = t >> 4, oq = t & 15;
    const int o = oq * 2;
    const int gb = blockIdx.y * 16 + b;
    const int go = blockIdx.x * 32 + o;
    float r0 = red[0][0][b][o]   + red[1][0][b][o]   + red[2][0][b][o]   + red[3][0][b][o];
    float i0 = red[0][1][b][o]   + red[1][1][b][o]   + red[2][1][b][o]   + red[3][1][b][o];
    float r1 = red[0][0][b][o+1] + red[1][0][b][o+1] + red[2][0][b][o+1] + red[3][0][b][o+1];
    float i1 = red[0][1][b][o+1] + red[1][1][b][o+1] + red[2][1][b][o+1] + red[3][1][b][o+1];
    float4 v;
    v.x = r0 + b_re[go];     v.y = i0 + b_im[go];
    v.z = r1 + b_re[go + 1]; v.w = i1 + b_im[go + 1];
    *(float4*)(out + ((size_t)gb * O_ + go) * 2) = v;
}

extern "C" void kernel_launch(void* const* d_in, const int* in_sizes, int n_in,
                              void* d_out, int out_size, void* d_ws, size_t ws_size,
                              hipStream_t stream) {
    const float* x_re = (const float*)d_in[0];
    const float* x_im = (const float*)d_in[1];
    const float* G_re = (const float*)d_in[2];
    const float* G_im = (const float*)d_in[3];
    const float* s_re = (const float*)d_in[4];
    const float* s_im = (const float*)d_in[5];
    const float* W_re = (const float*)d_in[6];
    const float* W_im = (const float*)d_in[7];
    const float* b_re = (const float*)d_in[8];
    const float* b_im = (const float*)d_in[9];
    float* out = (float*)d_out;

    u16* Xfr  = (u16*)d_ws;
    u16* Xfi  = Xfr  + (size_t)B_ * I_;
    u16* GTfr = Xfi  + (size_t)B_ * I_;
    u16* GTfi = GTfr + (size_t)N_ * I_;
    u16* WTfr = GTfi + (size_t)N_ * I_;
    u16* WTfi = WTfr + (size_t)O_ * N_;
    u16* Pfr  = WTfi + (size_t)O_ * N_;
    u16* Pfi  = Pfr  + (size_t)B_ * N_;
    float* xsq_re = (float*)(Pfi + (size_t)B_ * N_);
    float* xsq_im = xsq_re + B_;
    float* gsq_re_part = xsq_im + B_;        // [4][N_]
    float* gsq_im_part = gsq_re_part + 4 * N_;

    prep_kernel<<<288, 256, 0, stream>>>(
        x_re, x_im, G_re, G_im, W_re, W_im,
        Xfr, Xfi, GTfr, GTfi, WTfr, WTfi,
        xsq_re, xsq_im, gsq_re_part, gsq_im_part);

    phi_mfma<<<dim3(N_ / 64, B_ / 64, 2), 256, 0, stream>>>(
        Xfr, Xfi, GTfr, GTfi, xsq_re, xsq_im, gsq_re_part, gsq_im_part,
        s_re, s_im, Pfr, Pfi);

    y_mfma<<<dim3(O_ / 32, B_ / 16), 256, 0, stream>>>(
        Pfr, Pfi, WTfr, WTfi, b_re, b_im, out);
}